// Round 16
// baseline (152.658 us; speedup 1.0000x reference)
//
#include <hip/hip_runtime.h>
#include <hip/hip_fp16.h>
#include <math.h>

#define IN_DIM   128
#define OUT_DIM  128
#define FEAT_DIM 64
#define NB       64     // nodes per k_linear block
#define SCH      256    // scan chunk size == dsts per bucket

typedef _Float16 h2v __attribute__((ext_vector_type(2)));

__device__ __forceinline__ float2 h2f2(unsigned u) {
    __half2 h = *reinterpret_cast<const __half2*>(&u);
    return __half22float2(h);
}
__device__ __forceinline__ unsigned f2h2(float a, float b) {
    __half2 h = __floats2half2_rn(a, b);
    return *reinterpret_cast<unsigned*>(&h);
}
// c += dot(half2 a, half2 b) with fp32 accumulate (V_DOT2_F32_F16)
__device__ __forceinline__ float dot2(unsigned a, unsigned b, float c) {
#if __has_builtin(__builtin_amdgcn_fdot2)
    return __builtin_amdgcn_fdot2(*reinterpret_cast<h2v*>(&a),
                                  *reinterpret_cast<h2v*>(&b), c, false);
#else
    float2 fa = h2f2(a), fb = h2f2(b);
    return c + fa.x * fb.x + fa.y * fb.y;
#endif
}

// ---------------------------------------------------------------------------
// k_wt: pack W_fc / W_dst as fp16 k-pairs.  Wfp[k2][c] = half2(W[2k2][c],
// W[2k2+1][c]).  Wfp: 64x128 u32 = 32 KB (L1-resident), Wdp: 32x128 = 16 KB.
// ---------------------------------------------------------------------------
__global__ __launch_bounds__(256) void k_wt(const float* __restrict__ Wfc,
                                            const float* __restrict__ Wdst,
                                            unsigned* __restrict__ Wfp,
                                            unsigned* __restrict__ Wdp) {
    int idx = blockIdx.x * 256 + threadIdx.x;       // 48 blocks
    if (idx < 8192) {               // 64 k2 x 128 c
        int k2 = idx >> 7, c = idx & 127;
        Wfp[idx] = f2h2(Wfc[(2 * k2) * 128 + c], Wfc[(2 * k2 + 1) * 128 + c]);
    } else if (idx < 12288) {       // 32 k2 x 128 c
        int i2 = idx - 8192;
        int k2 = i2 >> 7, c = i2 & 127;
        Wdp[i2] = f2h2(Wdst[(2 * k2) * 128 + c], Wdst[(2 * k2 + 1) * 128 + c]);
    }
}

// ---------------------------------------------------------------------------
// z = fp16(h @ W_fc) ; dz = fp16(feat @ W_dst) — both via v_dot2_f32_f16.
// 256 threads/block, 64 nodes/block; grid = 2*nbz (z blocks, then dz blocks).
// NO fused histogram (r3/r15 lesson: scatter-atomic tails poison the kernel).
// ---------------------------------------------------------------------------
__global__ __launch_bounds__(256) void k_linear(
        const float* __restrict__ h, const float* __restrict__ feat,
        const unsigned* __restrict__ Wfp, const unsigned* __restrict__ Wdp,
        unsigned short* __restrict__ z_h, unsigned short* __restrict__ dz_h,
        int N, int nbz) {
    int t  = threadIdx.x;        // 0..255
    int c  = t & 31;             // cols 4c..4c+3
    int j0 = t >> 5;             // 0..7 -> nodes n0 + 8*j0 + jj
    int b  = blockIdx.x;
    bool do_z = (b < nbz);
    int n0 = (do_z ? b : b - nbz) * NB;

    __shared__ uint2 sh[NB * 32];   // 16 KB max (z); dz uses half

    float4 acc[8];
#pragma unroll
    for (int jj = 0; jj < 8; ++jj) acc[jj] = make_float4(0.f, 0.f, 0.f, 0.f);

    if (do_z) {
        // stage h tile fp16: [node][32] uint2 (uint2 = 2 k-pairs = 4 k)
        for (int i = t; i < NB * 32; i += 256) {
            int row = i >> 5, col = i & 31;
            int n = min(n0 + row, N - 1);
            float4 v = ((const float4*)(h + (size_t)n * IN_DIM))[col];
            sh[i] = make_uint2(f2h2(v.x, v.y), f2h2(v.z, v.w));
        }
        __syncthreads();

        const uint4* Wp4 = (const uint4*)Wfp;   // [k2][32] uint4
#pragma unroll 2
        for (int k4 = 0; k4 < 32; ++k4) {
            uint4 wA = Wp4[(size_t)(2 * k4) * 32 + c];       // k-pair 2k4
            uint4 wB = Wp4[(size_t)(2 * k4 + 1) * 32 + c];   // k-pair 2k4+1
#pragma unroll
            for (int jj = 0; jj < 8; ++jj) {
                uint2 q = sh[(j0 * 8 + jj) * 32 + k4];
                acc[jj].x = dot2(q.y, wB.x, dot2(q.x, wA.x, acc[jj].x));
                acc[jj].y = dot2(q.y, wB.y, dot2(q.x, wA.y, acc[jj].y));
                acc[jj].z = dot2(q.y, wB.z, dot2(q.x, wA.z, acc[jj].z));
                acc[jj].w = dot2(q.y, wB.w, dot2(q.x, wA.w, acc[jj].w));
            }
        }
#pragma unroll
        for (int jj = 0; jj < 8; ++jj) {
            int n = n0 + j0 * 8 + jj;
            if (n < N) {
                uint2 pk = make_uint2(f2h2(acc[jj].x, acc[jj].y),
                                      f2h2(acc[jj].z, acc[jj].w));
                ((uint2*)(z_h + (size_t)n * OUT_DIM))[c] = pk;
            }
        }
    } else {
        // stage feat tile fp16: [node][16] uint2
        for (int i = t; i < NB * 16; i += 256) {
            int row = i >> 4, col = i & 15;
            int n = min(n0 + row, N - 1);
            float4 v = ((const float4*)(feat + (size_t)n * FEAT_DIM))[col];
            sh[i] = make_uint2(f2h2(v.x, v.y), f2h2(v.z, v.w));
        }
        __syncthreads();

        const uint4* Wd4 = (const uint4*)Wdp;   // [k2][32] uint4
#pragma unroll 2
        for (int k4 = 0; k4 < 16; ++k4) {
            uint4 wA = Wd4[(size_t)(2 * k4) * 32 + c];
            uint4 wB = Wd4[(size_t)(2 * k4 + 1) * 32 + c];
#pragma unroll
            for (int jj = 0; jj < 8; ++jj) {
                uint2 q = sh[(j0 * 8 + jj) * 16 + k4];
                acc[jj].x = dot2(q.y, wB.x, dot2(q.x, wA.x, acc[jj].x));
                acc[jj].y = dot2(q.y, wB.y, dot2(q.x, wA.y, acc[jj].y));
                acc[jj].z = dot2(q.y, wB.z, dot2(q.x, wA.z, acc[jj].z));
                acc[jj].w = dot2(q.y, wB.w, dot2(q.x, wA.w, acc[jj].w));
            }
        }
#pragma unroll
        for (int jj = 0; jj < 8; ++jj) {
            int n = n0 + j0 * 8 + jj;
            if (n < N) {
                uint2 pk = make_uint2(f2h2(acc[jj].x, acc[jj].y),
                                      f2h2(acc[jj].z, acc[jj].w));
                ((uint2*)(dz_h + (size_t)n * OUT_DIM))[c] = pk;
            }
        }
    }
}

// ---------------------------------------------------------------------------
// CSR build: histogram -> scan -> bucketed counting sort (k_bin + k_sort)
// ---------------------------------------------------------------------------
__global__ void k_hist(const int* __restrict__ dst, unsigned* __restrict__ counts, int E) {
    for (int i = blockIdx.x * blockDim.x + threadIdx.x; i < E; i += gridDim.x * blockDim.x)
        atomicAdd(&counts[dst[i]], 1u);
}

__global__ __launch_bounds__(SCH) void k_scan1(const unsigned* __restrict__ counts,
                                               unsigned* __restrict__ partials, int N) {
    int b = blockIdx.x, t = threadIdx.x;
    int idx = b * SCH + t;
    unsigned v = (idx < N) ? counts[idx] : 0u;
#pragma unroll
    for (int off = 32; off; off >>= 1) v += __shfl_xor(v, off);   // wave64 reduce
    __shared__ unsigned sw[SCH / 64];
    if ((t & 63) == 0) sw[t >> 6] = v;
    __syncthreads();
    if (t == 0) {
        unsigned s = 0;
#pragma unroll
        for (int i = 0; i < SCH / 64; ++i) s += sw[i];
        partials[b] = s;
    }
}

__global__ __launch_bounds__(1024) void k_scan2(unsigned* __restrict__ partials, int nblk) {
    __shared__ unsigned s[1024];
    int t = threadIdx.x;
    unsigned v = (t < nblk) ? partials[t] : 0u;
    s[t] = v;
    __syncthreads();
    for (int off = 1; off < 1024; off <<= 1) {
        unsigned u = (t >= off) ? s[t - off] : 0u;
        __syncthreads();
        s[t] += u;
        __syncthreads();
    }
    if (t < nblk) partials[t] = s[t] - v;
}

// also seeds bucket_cursor[b] = offsets[b*256]
__global__ __launch_bounds__(SCH) void k_scan3(const unsigned* __restrict__ counts,
                                               const unsigned* __restrict__ partials,
                                               unsigned* __restrict__ offsets,
                                               unsigned* __restrict__ bucket_cursor, int N) {
    int b = blockIdx.x, t = threadIdx.x;
    int idx = b * SCH + t;
    unsigned v = (idx < N) ? counts[idx] : 0u;
    __shared__ unsigned s[SCH];
    s[t] = v;
    __syncthreads();
    for (int off = 1; off < SCH; off <<= 1) {
        unsigned u = (t >= off) ? s[t - off] : 0u;
        __syncthreads();
        s[t] += u;
        __syncthreads();
    }
    unsigned base = partials[b];
    if (idx < N)  offsets[idx] = base + s[t] - v;
    if (idx == N - 1) offsets[N] = base + s[t];
    if (t == 0) bucket_cursor[b] = base;
}

// counting sort stage 1: bin edges by bucket (dst>>8); payload packed u32:
// src (24 bits) | local-dst (8 bits) << 24.  Line-filling grouped writes.
__global__ __launch_bounds__(256) void k_bin(
        const int* __restrict__ dst, const int* __restrict__ src,
        unsigned* __restrict__ bucket_cursor, unsigned* __restrict__ binned,
        int E, int nbkt) {
    __shared__ unsigned hist[256];
    __shared__ unsigned base[256];
    __shared__ unsigned cur[256];
    int t = threadIdx.x;
    int per = (E + gridDim.x - 1) / gridDim.x;
    int lo = blockIdx.x * per;
    int hi = min(E, lo + per);

    hist[t] = 0;
    cur[t]  = 0;
    __syncthreads();
    for (int i = lo + t; i < hi; i += 256)
        atomicAdd(&hist[dst[i] >> 8], 1u);
    __syncthreads();
    if (t < nbkt) base[t] = atomicAdd(&bucket_cursor[t], hist[t]);
    __syncthreads();
    for (int i = lo + t; i < hi; i += 256) {
        int d = dst[i];
        int bk = d >> 8;
        unsigned slot = base[bk] + atomicAdd(&cur[bk], 1u);
        binned[slot] = (unsigned)src[i] | ((unsigned)(d & 255) << 24);
    }
}

// counting sort stage 2: block b owns dst range [b*256, +256) + its csr window
__global__ __launch_bounds__(256) void k_sort(
        const unsigned* __restrict__ binned, const unsigned* __restrict__ offsets,
        unsigned* __restrict__ csr, int N) {
    __shared__ unsigned off[257];
    __shared__ unsigned cur[256];
    int b = blockIdx.x, t = threadIdx.x;
    int d0 = b << 8;
    int nd = min(N - d0, 256);
    if (t < nd) off[t] = offsets[d0 + t];
    if (t == 0) off[nd] = offsets[d0 + nd];
    cur[t] = 0;
    __syncthreads();
    unsigned lo = off[0], hi = off[nd];
    for (unsigned i = lo + t; i < hi; i += 256) {
        unsigned e = binned[i];
        int ld = (int)(e >> 24);
        unsigned pos = off[ld] + atomicAdd(&cur[ld], 1u);
        csr[pos] = e & 0xFFFFFFu;
    }
}

// ---------------------------------------------------------------------------
// Fused attention + aggregation. One 64-lane wave per node (4 nodes/block).
// 16 lanes per edge; z AND dz rows in FP16 (256 B/row, one uint4/lane).
// Edge dot via v_dot2_f32_f16 chains (4/slot); unpack only for accumulate.
// ---------------------------------------------------------------------------
__global__ __launch_bounds__(256) void k_node(
        const unsigned short* __restrict__ z_h, const unsigned short* __restrict__ dz_h,
        const unsigned* __restrict__ offsets, const unsigned* __restrict__ csr,
        float* __restrict__ out, int N) {
    int lane = threadIdx.x & 63;
    int wv   = threadIdx.x >> 6;          // 0..3
    int g    = lane >> 4;                 // edge slot 0..3
    int l16  = lane & 15;                 // row chunk: dims [8*l16, 8*l16+8)
    int n = blockIdx.x * 4 + wv;
    if (n >= N) return;

    unsigned start = offsets[n];
    int deg = (int)(offsets[n + 1] - start);
    float4* orow = (float4*)(out + (size_t)n * OUT_DIM);
    if (deg == 0) {
        if (g == 0) {
            orow[2 * l16]     = make_float4(0.f, 0.f, 0.f, 0.f);
            orow[2 * l16 + 1] = make_float4(0.f, 0.f, 0.f, 0.f);
        }
        return;
    }

    uint4 dq = ((const uint4*)(dz_h + (size_t)n * OUT_DIM))[l16];  // 8 fp16 dims

    float a[8];
#pragma unroll
    for (int k = 0; k < 8; ++k) a[k] = 0.f;
    float denom = 0.f;

    for (int i = 0; i < deg; i += 8) {
        int eA = i + g;
        int eB = i + 4 + g;
        bool vA = eA < deg;
        bool vB = eB < deg;
        int sA = vA ? (int)csr[start + eA] : 0;
        int sB = vB ? (int)csr[start + eB] : 0;
        uint4 qA = ((const uint4*)(z_h + (size_t)sA * OUT_DIM))[l16];
        uint4 qB = ((const uint4*)(z_h + (size_t)sB * OUT_DIM))[l16];

        float pA = dot2(qA.w, dq.w, dot2(qA.z, dq.z, dot2(qA.y, dq.y, dot2(qA.x, dq.x, 0.f))));
        float pB = dot2(qB.w, dq.w, dot2(qB.z, dq.z, dot2(qB.y, dq.y, dot2(qB.x, dq.x, 0.f))));
#pragma unroll
        for (int off = 1; off <= 8; off <<= 1) {   // reduce within 16-lane group
            pA += __shfl_xor(pA, off);
            pB += __shfl_xor(pB, off);
        }
        float wA = vA ? __expf(pA) : 0.f;
        float wB = vB ? __expf(pB) : 0.f;
        denom += wA + wB;

        float2 zA01 = h2f2(qA.x), zA23 = h2f2(qA.y), zA45 = h2f2(qA.z), zA67 = h2f2(qA.w);
        float2 zB01 = h2f2(qB.x), zB23 = h2f2(qB.y), zB45 = h2f2(qB.z), zB67 = h2f2(qB.w);
        a[0] += wA * zA01.x + wB * zB01.x;  a[1] += wA * zA01.y + wB * zB01.y;
        a[2] += wA * zA23.x + wB * zB23.x;  a[3] += wA * zA23.y + wB * zB23.y;
        a[4] += wA * zA45.x + wB * zB45.x;  a[5] += wA * zA45.y + wB * zB45.y;
        a[6] += wA * zA67.x + wB * zB67.x;  a[7] += wA * zA67.y + wB * zB67.y;
    }

    // fold the 4 edge-groups together (lanes l, l^16, l^32, l^48)
#pragma unroll
    for (int off = 16; off <= 32; off <<= 1) {
#pragma unroll
        for (int k = 0; k < 8; ++k) a[k] += __shfl_xor(a[k], off);
        denom += __shfl_xor(denom, off);
    }

    if (g == 0) {
        float inv = 1.f / denom;
        orow[2 * l16]     = make_float4(a[0] * inv, a[1] * inv, a[2] * inv, a[3] * inv);
        orow[2 * l16 + 1] = make_float4(a[4] * inv, a[5] * inv, a[6] * inv, a[7] * inv);
    }
}

// ---------------------------------------------------------------------------
extern "C" void kernel_launch(void* const* d_in, const int* in_sizes, int n_in,
                              void* d_out, int out_size, void* d_ws, size_t ws_size,
                              hipStream_t stream) {
    const float* h    = (const float*)d_in[0];
    const float* feat = (const float*)d_in[1];
    const float* Wfc  = (const float*)d_in[2];
    const float* Wdst = (const float*)d_in[3];
    const int*   src  = (const int*)d_in[4];
    const int*   dst  = (const int*)d_in[5];
    float*       out  = (float*)d_out;

    int N = in_sizes[0] / IN_DIM;
    int E = in_sizes[4];

    char* ws = (char*)d_ws;
    unsigned short* z_h  = (unsigned short*)ws; ws += (size_t)N * OUT_DIM * sizeof(unsigned short);
    unsigned short* dz_h = (unsigned short*)ws; ws += (size_t)N * OUT_DIM * sizeof(unsigned short);
    unsigned* Wfp      = (unsigned*)ws; ws += (size_t)8192 * sizeof(unsigned);
    unsigned* Wdp      = (unsigned*)ws; ws += (size_t)4096 * sizeof(unsigned);
    unsigned* binned   = (unsigned*)ws; ws += (size_t)E * sizeof(unsigned);
    unsigned* counts   = (unsigned*)ws; ws += (size_t)N * sizeof(unsigned);
    unsigned* offsets  = (unsigned*)ws; ws += (size_t)(N + 1) * sizeof(unsigned);
    unsigned* partials = (unsigned*)ws; ws += (size_t)1024 * sizeof(unsigned);
    unsigned* bcursor  = (unsigned*)ws; ws += (size_t)1024 * sizeof(unsigned);
    unsigned* csr      = (unsigned*)ws;

    int nbz  = (N + NB - 1) / NB;       // 782
    int nblk = (N + SCH - 1) / SCH;     // 196 buckets

    hipMemsetAsync(counts, 0, (size_t)N * sizeof(unsigned), stream);

    k_wt     <<<48, 256, 0, stream>>>(Wfc, Wdst, Wfp, Wdp);
    k_linear <<<2 * nbz, 256, 0, stream>>>(h, feat, Wfp, Wdp, z_h, dz_h, N, nbz);
    k_hist   <<<1024, 256, 0, stream>>>(dst, counts, E);
    k_scan1  <<<nblk, SCH, 0, stream>>>(counts, partials, N);
    k_scan2  <<<1, 1024, 0, stream>>>(partials, nblk);
    k_scan3  <<<nblk, SCH, 0, stream>>>(counts, partials, offsets, bcursor, N);
    k_bin    <<<512, 256, 0, stream>>>(dst, src, bcursor, binned, E, nblk);
    k_sort   <<<nblk, 256, 0, stream>>>(binned, offsets, csr, N);
    k_node   <<<(N + 3) / 4, 256, 0, stream>>>(z_h, dz_h, offsets, csr, out, N);
}

// Round 17
// 150.678 us; speedup vs baseline: 1.0131x; 1.0131x over previous
//
#include <hip/hip_runtime.h>
#include <hip/hip_fp16.h>
#include <math.h>

#define IN_DIM   128
#define OUT_DIM  128
#define FEAT_DIM 64
#define NB       64     // nodes per k_linear block
#define SCH      256    // scan chunk size == dsts per bucket

typedef _Float16 h2v __attribute__((ext_vector_type(2)));

__device__ __forceinline__ float2 h2f2(unsigned u) {
    __half2 h = *reinterpret_cast<const __half2*>(&u);
    return __half22float2(h);
}
__device__ __forceinline__ unsigned f2h2(float a, float b) {
    __half2 h = __floats2half2_rn(a, b);
    return *reinterpret_cast<unsigned*>(&h);
}
// c += dot(half2 a, half2 b) with fp32 accumulate (V_DOT2_F32_F16)
__device__ __forceinline__ float dot2(unsigned a, unsigned b, float c) {
#if __has_builtin(__builtin_amdgcn_fdot2)
    return __builtin_amdgcn_fdot2(*reinterpret_cast<h2v*>(&a),
                                  *reinterpret_cast<h2v*>(&b), c, false);
#else
    float2 fa = h2f2(a), fb = h2f2(b);
    return c + fa.x * fb.x + fa.y * fb.y;
#endif
}

// ---------------------------------------------------------------------------
// k_wt: pack W_fc / W_dst as fp16 k-pairs AND zero the counts array
// (replaces a pathologically slow 40-us runtime fillBuffer dispatch).
// ---------------------------------------------------------------------------
__global__ __launch_bounds__(256) void k_wt(const float* __restrict__ Wfc,
                                            const float* __restrict__ Wdst,
                                            unsigned* __restrict__ Wfp,
                                            unsigned* __restrict__ Wdp,
                                            unsigned* __restrict__ counts, int N) {
    int idx = blockIdx.x * 256 + threadIdx.x;       // 48 blocks = 12288 threads
    if (idx < 8192) {               // 64 k2 x 128 c
        int k2 = idx >> 7, c = idx & 127;
        Wfp[idx] = f2h2(Wfc[(2 * k2) * 128 + c], Wfc[(2 * k2 + 1) * 128 + c]);
    } else if (idx < 12288) {       // 32 k2 x 128 c
        int i2 = idx - 8192;
        int k2 = i2 >> 7, c = i2 & 127;
        Wdp[i2] = f2h2(Wdst[(2 * k2) * 128 + c], Wdst[(2 * k2 + 1) * 128 + c]);
    }
    // zero counts: grid-stride uint4 clear (N/4 uint4s), then scalar tail
    int n4 = N >> 2;
    uint4* c4 = (uint4*)counts;
    for (int i = idx; i < n4; i += 12288)
        c4[i] = make_uint4(0u, 0u, 0u, 0u);
    for (int i = 4 * n4 + idx; i < N; i += 12288)
        counts[i] = 0u;
}

// ---------------------------------------------------------------------------
// z = fp16(h @ W_fc) ; dz = fp16(feat @ W_dst) — both via v_dot2_f32_f16.
// 256 threads/block, 64 nodes/block; grid = 2*nbz (z blocks, then dz blocks).
// NO fused histogram (r3/r15 lesson: scatter-atomic tails poison the kernel).
// ---------------------------------------------------------------------------
__global__ __launch_bounds__(256) void k_linear(
        const float* __restrict__ h, const float* __restrict__ feat,
        const unsigned* __restrict__ Wfp, const unsigned* __restrict__ Wdp,
        unsigned short* __restrict__ z_h, unsigned short* __restrict__ dz_h,
        int N, int nbz) {
    int t  = threadIdx.x;        // 0..255
    int c  = t & 31;             // cols 4c..4c+3
    int j0 = t >> 5;             // 0..7 -> nodes n0 + 8*j0 + jj
    int b  = blockIdx.x;
    bool do_z = (b < nbz);
    int n0 = (do_z ? b : b - nbz) * NB;

    __shared__ uint2 sh[NB * 32];   // 16 KB max (z); dz uses half

    float4 acc[8];
#pragma unroll
    for (int jj = 0; jj < 8; ++jj) acc[jj] = make_float4(0.f, 0.f, 0.f, 0.f);

    if (do_z) {
        // stage h tile fp16: [node][32] uint2 (uint2 = 2 k-pairs = 4 k)
        for (int i = t; i < NB * 32; i += 256) {
            int row = i >> 5, col = i & 31;
            int n = min(n0 + row, N - 1);
            float4 v = ((const float4*)(h + (size_t)n * IN_DIM))[col];
            sh[i] = make_uint2(f2h2(v.x, v.y), f2h2(v.z, v.w));
        }
        __syncthreads();

        const uint4* Wp4 = (const uint4*)Wfp;   // [k2][32] uint4
#pragma unroll 2
        for (int k4 = 0; k4 < 32; ++k4) {
            uint4 wA = Wp4[(size_t)(2 * k4) * 32 + c];       // k-pair 2k4
            uint4 wB = Wp4[(size_t)(2 * k4 + 1) * 32 + c];   // k-pair 2k4+1
#pragma unroll
            for (int jj = 0; jj < 8; ++jj) {
                uint2 q = sh[(j0 * 8 + jj) * 32 + k4];
                acc[jj].x = dot2(q.y, wB.x, dot2(q.x, wA.x, acc[jj].x));
                acc[jj].y = dot2(q.y, wB.y, dot2(q.x, wA.y, acc[jj].y));
                acc[jj].z = dot2(q.y, wB.z, dot2(q.x, wA.z, acc[jj].z));
                acc[jj].w = dot2(q.y, wB.w, dot2(q.x, wA.w, acc[jj].w));
            }
        }
#pragma unroll
        for (int jj = 0; jj < 8; ++jj) {
            int n = n0 + j0 * 8 + jj;
            if (n < N) {
                uint2 pk = make_uint2(f2h2(acc[jj].x, acc[jj].y),
                                      f2h2(acc[jj].z, acc[jj].w));
                ((uint2*)(z_h + (size_t)n * OUT_DIM))[c] = pk;
            }
        }
    } else {
        // stage feat tile fp16: [node][16] uint2
        for (int i = t; i < NB * 16; i += 256) {
            int row = i >> 4, col = i & 15;
            int n = min(n0 + row, N - 1);
            float4 v = ((const float4*)(feat + (size_t)n * FEAT_DIM))[col];
            sh[i] = make_uint2(f2h2(v.x, v.y), f2h2(v.z, v.w));
        }
        __syncthreads();

        const uint4* Wd4 = (const uint4*)Wdp;   // [k2][32] uint4
#pragma unroll 2
        for (int k4 = 0; k4 < 16; ++k4) {
            uint4 wA = Wd4[(size_t)(2 * k4) * 32 + c];
            uint4 wB = Wd4[(size_t)(2 * k4 + 1) * 32 + c];
#pragma unroll
            for (int jj = 0; jj < 8; ++jj) {
                uint2 q = sh[(j0 * 8 + jj) * 16 + k4];
                acc[jj].x = dot2(q.y, wB.x, dot2(q.x, wA.x, acc[jj].x));
                acc[jj].y = dot2(q.y, wB.y, dot2(q.x, wA.y, acc[jj].y));
                acc[jj].z = dot2(q.y, wB.z, dot2(q.x, wA.z, acc[jj].z));
                acc[jj].w = dot2(q.y, wB.w, dot2(q.x, wA.w, acc[jj].w));
            }
        }
#pragma unroll
        for (int jj = 0; jj < 8; ++jj) {
            int n = n0 + j0 * 8 + jj;
            if (n < N) {
                uint2 pk = make_uint2(f2h2(acc[jj].x, acc[jj].y),
                                      f2h2(acc[jj].z, acc[jj].w));
                ((uint2*)(dz_h + (size_t)n * OUT_DIM))[c] = pk;
            }
        }
    }
}

// ---------------------------------------------------------------------------
// CSR build: histogram -> scan -> bucketed counting sort (k_bin + k_sort)
// ---------------------------------------------------------------------------
__global__ void k_hist(const int* __restrict__ dst, unsigned* __restrict__ counts, int E) {
    for (int i = blockIdx.x * blockDim.x + threadIdx.x; i < E; i += gridDim.x * blockDim.x)
        atomicAdd(&counts[dst[i]], 1u);
}

__global__ __launch_bounds__(SCH) void k_scan1(const unsigned* __restrict__ counts,
                                               unsigned* __restrict__ partials, int N) {
    int b = blockIdx.x, t = threadIdx.x;
    int idx = b * SCH + t;
    unsigned v = (idx < N) ? counts[idx] : 0u;
#pragma unroll
    for (int off = 32; off; off >>= 1) v += __shfl_xor(v, off);   // wave64 reduce
    __shared__ unsigned sw[SCH / 64];
    if ((t & 63) == 0) sw[t >> 6] = v;
    __syncthreads();
    if (t == 0) {
        unsigned s = 0;
#pragma unroll
        for (int i = 0; i < SCH / 64; ++i) s += sw[i];
        partials[b] = s;
    }
}

__global__ __launch_bounds__(1024) void k_scan2(unsigned* __restrict__ partials, int nblk) {
    __shared__ unsigned s[1024];
    int t = threadIdx.x;
    unsigned v = (t < nblk) ? partials[t] : 0u;
    s[t] = v;
    __syncthreads();
    for (int off = 1; off < 1024; off <<= 1) {
        unsigned u = (t >= off) ? s[t - off] : 0u;
        __syncthreads();
        s[t] += u;
        __syncthreads();
    }
    if (t < nblk) partials[t] = s[t] - v;
}

// also seeds bucket_cursor[b] = offsets[b*256]
__global__ __launch_bounds__(SCH) void k_scan3(const unsigned* __restrict__ counts,
                                               const unsigned* __restrict__ partials,
                                               unsigned* __restrict__ offsets,
                                               unsigned* __restrict__ bucket_cursor, int N) {
    int b = blockIdx.x, t = threadIdx.x;
    int idx = b * SCH + t;
    unsigned v = (idx < N) ? counts[idx] : 0u;
    __shared__ unsigned s[SCH];
    s[t] = v;
    __syncthreads();
    for (int off = 1; off < SCH; off <<= 1) {
        unsigned u = (t >= off) ? s[t - off] : 0u;
        __syncthreads();
        s[t] += u;
        __syncthreads();
    }
    unsigned base = partials[b];
    if (idx < N)  offsets[idx] = base + s[t] - v;
    if (idx == N - 1) offsets[N] = base + s[t];
    if (t == 0) bucket_cursor[b] = base;
}

// counting sort stage 1: bin edges by bucket (dst>>8); payload packed u32:
// src (24 bits) | local-dst (8 bits) << 24.  Line-filling grouped writes.
__global__ __launch_bounds__(256) void k_bin(
        const int* __restrict__ dst, const int* __restrict__ src,
        unsigned* __restrict__ bucket_cursor, unsigned* __restrict__ binned,
        int E, int nbkt) {
    __shared__ unsigned hist[256];
    __shared__ unsigned base[256];
    __shared__ unsigned cur[256];
    int t = threadIdx.x;
    int per = (E + gridDim.x - 1) / gridDim.x;
    int lo = blockIdx.x * per;
    int hi = min(E, lo + per);

    hist[t] = 0;
    cur[t]  = 0;
    __syncthreads();
    for (int i = lo + t; i < hi; i += 256)
        atomicAdd(&hist[dst[i] >> 8], 1u);
    __syncthreads();
    if (t < nbkt) base[t] = atomicAdd(&bucket_cursor[t], hist[t]);
    __syncthreads();
    for (int i = lo + t; i < hi; i += 256) {
        int d = dst[i];
        int bk = d >> 8;
        unsigned slot = base[bk] + atomicAdd(&cur[bk], 1u);
        binned[slot] = (unsigned)src[i] | ((unsigned)(d & 255) << 24);
    }
}

// counting sort stage 2: block b owns dst range [b*256, +256) + its csr window
__global__ __launch_bounds__(256) void k_sort(
        const unsigned* __restrict__ binned, const unsigned* __restrict__ offsets,
        unsigned* __restrict__ csr, int N) {
    __shared__ unsigned off[257];
    __shared__ unsigned cur[256];
    int b = blockIdx.x, t = threadIdx.x;
    int d0 = b << 8;
    int nd = min(N - d0, 256);
    if (t < nd) off[t] = offsets[d0 + t];
    if (t == 0) off[nd] = offsets[d0 + nd];
    cur[t] = 0;
    __syncthreads();
    unsigned lo = off[0], hi = off[nd];
    for (unsigned i = lo + t; i < hi; i += 256) {
        unsigned e = binned[i];
        int ld = (int)(e >> 24);
        unsigned pos = off[ld] + atomicAdd(&cur[ld], 1u);
        csr[pos] = e & 0xFFFFFFu;
    }
}

// ---------------------------------------------------------------------------
// Fused attention + aggregation. One 64-lane wave per node (4 nodes/block).
// 16 lanes per edge; z AND dz rows in FP16 (256 B/row, one uint4/lane).
// Edge dot via v_dot2_f32_f16 chains (4/slot); unpack only for accumulate.
// ---------------------------------------------------------------------------
__global__ __launch_bounds__(256) void k_node(
        const unsigned short* __restrict__ z_h, const unsigned short* __restrict__ dz_h,
        const unsigned* __restrict__ offsets, const unsigned* __restrict__ csr,
        float* __restrict__ out, int N) {
    int lane = threadIdx.x & 63;
    int wv   = threadIdx.x >> 6;          // 0..3
    int g    = lane >> 4;                 // edge slot 0..3
    int l16  = lane & 15;                 // row chunk: dims [8*l16, 8*l16+8)
    int n = blockIdx.x * 4 + wv;
    if (n >= N) return;

    unsigned start = offsets[n];
    int deg = (int)(offsets[n + 1] - start);
    float4* orow = (float4*)(out + (size_t)n * OUT_DIM);
    if (deg == 0) {
        if (g == 0) {
            orow[2 * l16]     = make_float4(0.f, 0.f, 0.f, 0.f);
            orow[2 * l16 + 1] = make_float4(0.f, 0.f, 0.f, 0.f);
        }
        return;
    }

    uint4 dq = ((const uint4*)(dz_h + (size_t)n * OUT_DIM))[l16];  // 8 fp16 dims

    float a[8];
#pragma unroll
    for (int k = 0; k < 8; ++k) a[k] = 0.f;
    float denom = 0.f;

    for (int i = 0; i < deg; i += 8) {
        int eA = i + g;
        int eB = i + 4 + g;
        bool vA = eA < deg;
        bool vB = eB < deg;
        int sA = vA ? (int)csr[start + eA] : 0;
        int sB = vB ? (int)csr[start + eB] : 0;
        uint4 qA = ((const uint4*)(z_h + (size_t)sA * OUT_DIM))[l16];
        uint4 qB = ((const uint4*)(z_h + (size_t)sB * OUT_DIM))[l16];

        float pA = dot2(qA.w, dq.w, dot2(qA.z, dq.z, dot2(qA.y, dq.y, dot2(qA.x, dq.x, 0.f))));
        float pB = dot2(qB.w, dq.w, dot2(qB.z, dq.z, dot2(qB.y, dq.y, dot2(qB.x, dq.x, 0.f))));
#pragma unroll
        for (int off = 1; off <= 8; off <<= 1) {   // reduce within 16-lane group
            pA += __shfl_xor(pA, off);
            pB += __shfl_xor(pB, off);
        }
        float wA = vA ? __expf(pA) : 0.f;
        float wB = vB ? __expf(pB) : 0.f;
        denom += wA + wB;

        float2 zA01 = h2f2(qA.x), zA23 = h2f2(qA.y), zA45 = h2f2(qA.z), zA67 = h2f2(qA.w);
        float2 zB01 = h2f2(qB.x), zB23 = h2f2(qB.y), zB45 = h2f2(qB.z), zB67 = h2f2(qB.w);
        a[0] += wA * zA01.x + wB * zB01.x;  a[1] += wA * zA01.y + wB * zB01.y;
        a[2] += wA * zA23.x + wB * zB23.x;  a[3] += wA * zA23.y + wB * zB23.y;
        a[4] += wA * zA45.x + wB * zB45.x;  a[5] += wA * zA45.y + wB * zB45.y;
        a[6] += wA * zA67.x + wB * zB67.x;  a[7] += wA * zA67.y + wB * zB67.y;
    }

    // fold the 4 edge-groups together (lanes l, l^16, l^32, l^48)
#pragma unroll
    for (int off = 16; off <= 32; off <<= 1) {
#pragma unroll
        for (int k = 0; k < 8; ++k) a[k] += __shfl_xor(a[k], off);
        denom += __shfl_xor(denom, off);
    }

    if (g == 0) {
        float inv = 1.f / denom;
        orow[2 * l16]     = make_float4(a[0] * inv, a[1] * inv, a[2] * inv, a[3] * inv);
        orow[2 * l16 + 1] = make_float4(a[4] * inv, a[5] * inv, a[6] * inv, a[7] * inv);
    }
}

// ---------------------------------------------------------------------------
extern "C" void kernel_launch(void* const* d_in, const int* in_sizes, int n_in,
                              void* d_out, int out_size, void* d_ws, size_t ws_size,
                              hipStream_t stream) {
    const float* h    = (const float*)d_in[0];
    const float* feat = (const float*)d_in[1];
    const float* Wfc  = (const float*)d_in[2];
    const float* Wdst = (const float*)d_in[3];
    const int*   src  = (const int*)d_in[4];
    const int*   dst  = (const int*)d_in[5];
    float*       out  = (float*)d_out;

    int N = in_sizes[0] / IN_DIM;
    int E = in_sizes[4];

    char* ws = (char*)d_ws;
    unsigned short* z_h  = (unsigned short*)ws; ws += (size_t)N * OUT_DIM * sizeof(unsigned short);
    unsigned short* dz_h = (unsigned short*)ws; ws += (size_t)N * OUT_DIM * sizeof(unsigned short);
    unsigned* Wfp      = (unsigned*)ws; ws += (size_t)8192 * sizeof(unsigned);
    unsigned* Wdp      = (unsigned*)ws; ws += (size_t)4096 * sizeof(unsigned);
    unsigned* binned   = (unsigned*)ws; ws += (size_t)E * sizeof(unsigned);
    unsigned* counts   = (unsigned*)ws; ws += (size_t)N * sizeof(unsigned);
    unsigned* offsets  = (unsigned*)ws; ws += (size_t)(N + 1) * sizeof(unsigned);
    unsigned* partials = (unsigned*)ws; ws += (size_t)1024 * sizeof(unsigned);
    unsigned* bcursor  = (unsigned*)ws; ws += (size_t)1024 * sizeof(unsigned);
    unsigned* csr      = (unsigned*)ws;

    int nbz  = (N + NB - 1) / NB;       // 782
    int nblk = (N + SCH - 1) / SCH;     // 196 buckets

    k_wt     <<<48, 256, 0, stream>>>(Wfc, Wdst, Wfp, Wdp, counts, N);
    k_linear <<<2 * nbz, 256, 0, stream>>>(h, feat, Wfp, Wdp, z_h, dz_h, N, nbz);
    k_hist   <<<1024, 256, 0, stream>>>(dst, counts, E);
    k_scan1  <<<nblk, SCH, 0, stream>>>(counts, partials, N);
    k_scan2  <<<1, 1024, 0, stream>>>(partials, nblk);
    k_scan3  <<<nblk, SCH, 0, stream>>>(counts, partials, offsets, bcursor, N);
    k_bin    <<<512, 256, 0, stream>>>(dst, src, bcursor, binned, E, nblk);
    k_sort   <<<nblk, 256, 0, stream>>>(binned, offsets, csr, N);
    k_node   <<<(N + 3) / 4, 256, 0, stream>>>(z_h, dz_h, offsets, csr, out, N);
}

// Round 18
// 123.401 us; speedup vs baseline: 1.2371x; 1.2210x over previous
//
#include <hip/hip_runtime.h>
#include <hip/hip_fp16.h>
#include <math.h>

#define IN_DIM   128
#define OUT_DIM  128
#define FEAT_DIM 64
#define NB       64     // nodes per k_linear block
#define EBUF     6144   // k_sortx LDS staging capacity (bucket mean 4083, 23 sigma)

typedef _Float16 h2v __attribute__((ext_vector_type(2)));

__device__ __forceinline__ float2 h2f2(unsigned u) {
    __half2 h = *reinterpret_cast<const __half2*>(&u);
    return __half22float2(h);
}
__device__ __forceinline__ unsigned f2h2(float a, float b) {
    __half2 h = __floats2half2_rn(a, b);
    return *reinterpret_cast<unsigned*>(&h);
}
// c += dot(half2 a, half2 b) with fp32 accumulate (V_DOT2_F32_F16)
__device__ __forceinline__ float dot2(unsigned a, unsigned b, float c) {
#if __has_builtin(__builtin_amdgcn_fdot2)
    return __builtin_amdgcn_fdot2(*reinterpret_cast<h2v*>(&a),
                                  *reinterpret_cast<h2v*>(&b), c, false);
#else
    float2 fa = h2f2(a), fb = h2f2(b);
    return c + fa.x * fb.x + fa.y * fb.y;
#endif
}

// ---------------------------------------------------------------------------
// k_wt: pack W_fc / W_dst as fp16 k-pairs; zero the 196 bucket counters.
// ---------------------------------------------------------------------------
__global__ __launch_bounds__(256) void k_wt(const float* __restrict__ Wfc,
                                            const float* __restrict__ Wdst,
                                            unsigned* __restrict__ Wfp,
                                            unsigned* __restrict__ Wdp,
                                            unsigned* __restrict__ bcounts) {
    int idx = blockIdx.x * 256 + threadIdx.x;       // 48 blocks = 12288 threads
    if (idx < 8192) {               // 64 k2 x 128 c
        int k2 = idx >> 7, c = idx & 127;
        Wfp[idx] = f2h2(Wfc[(2 * k2) * 128 + c], Wfc[(2 * k2 + 1) * 128 + c]);
    } else if (idx < 12288) {       // 32 k2 x 128 c
        int i2 = idx - 8192;
        int k2 = i2 >> 7, c = i2 & 127;
        Wdp[i2] = f2h2(Wdst[(2 * k2) * 128 + c], Wdst[(2 * k2 + 1) * 128 + c]);
    }
    if (idx < 256) bcounts[idx] = 0u;
}

// ---------------------------------------------------------------------------
// z = fp16(h @ W_fc) ; dz = fp16(feat @ W_dst) — both via v_dot2_f32_f16.
// 256 threads/block, 64 nodes/block; grid = 2*nbz (z blocks, then dz blocks).
// ---------------------------------------------------------------------------
__global__ __launch_bounds__(256) void k_linear(
        const float* __restrict__ h, const float* __restrict__ feat,
        const unsigned* __restrict__ Wfp, const unsigned* __restrict__ Wdp,
        unsigned short* __restrict__ z_h, unsigned short* __restrict__ dz_h,
        int N, int nbz) {
    int t  = threadIdx.x;        // 0..255
    int c  = t & 31;             // cols 4c..4c+3
    int j0 = t >> 5;             // 0..7 -> nodes n0 + 8*j0 + jj
    int b  = blockIdx.x;
    bool do_z = (b < nbz);
    int n0 = (do_z ? b : b - nbz) * NB;

    __shared__ uint2 sh[NB * 32];   // 16 KB max (z); dz uses half

    float4 acc[8];
#pragma unroll
    for (int jj = 0; jj < 8; ++jj) acc[jj] = make_float4(0.f, 0.f, 0.f, 0.f);

    if (do_z) {
        for (int i = t; i < NB * 32; i += 256) {
            int row = i >> 5, col = i & 31;
            int n = min(n0 + row, N - 1);
            float4 v = ((const float4*)(h + (size_t)n * IN_DIM))[col];
            sh[i] = make_uint2(f2h2(v.x, v.y), f2h2(v.z, v.w));
        }
        __syncthreads();

        const uint4* Wp4 = (const uint4*)Wfp;   // [k2][32] uint4
#pragma unroll 2
        for (int k4 = 0; k4 < 32; ++k4) {
            uint4 wA = Wp4[(size_t)(2 * k4) * 32 + c];
            uint4 wB = Wp4[(size_t)(2 * k4 + 1) * 32 + c];
#pragma unroll
            for (int jj = 0; jj < 8; ++jj) {
                uint2 q = sh[(j0 * 8 + jj) * 32 + k4];
                acc[jj].x = dot2(q.y, wB.x, dot2(q.x, wA.x, acc[jj].x));
                acc[jj].y = dot2(q.y, wB.y, dot2(q.x, wA.y, acc[jj].y));
                acc[jj].z = dot2(q.y, wB.z, dot2(q.x, wA.z, acc[jj].z));
                acc[jj].w = dot2(q.y, wB.w, dot2(q.x, wA.w, acc[jj].w));
            }
        }
#pragma unroll
        for (int jj = 0; jj < 8; ++jj) {
            int n = n0 + j0 * 8 + jj;
            if (n < N) {
                uint2 pk = make_uint2(f2h2(acc[jj].x, acc[jj].y),
                                      f2h2(acc[jj].z, acc[jj].w));
                ((uint2*)(z_h + (size_t)n * OUT_DIM))[c] = pk;
            }
        }
    } else {
        for (int i = t; i < NB * 16; i += 256) {
            int row = i >> 4, col = i & 15;
            int n = min(n0 + row, N - 1);
            float4 v = ((const float4*)(feat + (size_t)n * FEAT_DIM))[col];
            sh[i] = make_uint2(f2h2(v.x, v.y), f2h2(v.z, v.w));
        }
        __syncthreads();

        const uint4* Wd4 = (const uint4*)Wdp;   // [k2][32] uint4
#pragma unroll 2
        for (int k4 = 0; k4 < 16; ++k4) {
            uint4 wA = Wd4[(size_t)(2 * k4) * 32 + c];
            uint4 wB = Wd4[(size_t)(2 * k4 + 1) * 32 + c];
#pragma unroll
            for (int jj = 0; jj < 8; ++jj) {
                uint2 q = sh[(j0 * 8 + jj) * 16 + k4];
                acc[jj].x = dot2(q.y, wB.x, dot2(q.x, wA.x, acc[jj].x));
                acc[jj].y = dot2(q.y, wB.y, dot2(q.x, wA.y, acc[jj].y));
                acc[jj].z = dot2(q.y, wB.z, dot2(q.x, wA.z, acc[jj].z));
                acc[jj].w = dot2(q.y, wB.w, dot2(q.x, wA.w, acc[jj].w));
            }
        }
#pragma unroll
        for (int jj = 0; jj < 8; ++jj) {
            int n = n0 + j0 * 8 + jj;
            if (n < N) {
                uint2 pk = make_uint2(f2h2(acc[jj].x, acc[jj].y),
                                      f2h2(acc[jj].z, acc[jj].w));
                ((uint2*)(dz_h + (size_t)n * OUT_DIM))[c] = pk;
            }
        }
    }
}

// ---------------------------------------------------------------------------
// Bucket-first CSR build.  Bucket b = dst>>8 (196 buckets of 256 dsts).
// k_bhist: LDS-aggregated bucket histogram (196 counters only).
// ---------------------------------------------------------------------------
__global__ __launch_bounds__(256) void k_bhist(const int* __restrict__ dst,
                                               unsigned* __restrict__ bcounts,
                                               int E, int nbkt) {
    __shared__ unsigned hist[256];
    int t = threadIdx.x;
    hist[t] = 0;
    __syncthreads();
    for (int i = blockIdx.x * 256 + t; i < E; i += gridDim.x * 256)
        atomicAdd(&hist[dst[i] >> 8], 1u);
    __syncthreads();
    if (t < nbkt && hist[t]) atomicAdd(&bcounts[t], hist[t]);
}

// k_bscan: one block scans the 196 bucket counts -> bstart[0..nbkt], bcursor
__global__ __launch_bounds__(256) void k_bscan(const unsigned* __restrict__ bcounts,
                                               unsigned* __restrict__ bstart,
                                               unsigned* __restrict__ bcursor, int nbkt) {
    __shared__ unsigned s[256];
    int t = threadIdx.x;
    unsigned v = (t < nbkt) ? bcounts[t] : 0u;
    s[t] = v;
    __syncthreads();
    for (int off = 1; off < 256; off <<= 1) {
        unsigned u = (t >= off) ? s[t - off] : 0u;
        __syncthreads();
        s[t] += u;
        __syncthreads();
    }
    if (t < nbkt) {
        unsigned excl = s[t] - v;
        bstart[t]  = excl;
        bcursor[t] = excl;
        if (t == nbkt - 1) bstart[nbkt] = s[t];   // == E
    }
}

// k_bin: bin edges by bucket; payload = src | local_dst<<24; grouped writes.
__global__ __launch_bounds__(256) void k_bin(
        const int* __restrict__ dst, const int* __restrict__ src,
        unsigned* __restrict__ bcursor, unsigned* __restrict__ binned,
        int E, int nbkt) {
    __shared__ unsigned hist[256];
    __shared__ unsigned base[256];
    __shared__ unsigned cur[256];
    int t = threadIdx.x;
    int per = (E + gridDim.x - 1) / gridDim.x;
    int lo = blockIdx.x * per;
    int hi = min(E, lo + per);

    hist[t] = 0;
    cur[t]  = 0;
    __syncthreads();
    for (int i = lo + t; i < hi; i += 256)
        atomicAdd(&hist[dst[i] >> 8], 1u);
    __syncthreads();
    if (t < nbkt && hist[t]) base[t] = atomicAdd(&bcursor[t], hist[t]);
    __syncthreads();
    for (int i = lo + t; i < hi; i += 256) {
        int d = dst[i];
        int bk = d >> 8;
        unsigned slot = base[bk] + atomicAdd(&cur[bk], 1u);
        binned[slot] = (unsigned)src[i] | ((unsigned)(d & 255) << 24);
    }
}

// k_sortx: block b owns bucket b.  Stage bucket edges in LDS, per-dst LDS
// histogram + scan -> offsets[d0..d0+255] global + csr scatter into the
// block's private window.  No N-wide global histogram or scan needed.
__global__ __launch_bounds__(256) void k_sortx(
        const unsigned* __restrict__ binned, const unsigned* __restrict__ bstart,
        unsigned* __restrict__ offsets, unsigned* __restrict__ csr,
        int N, int E, int nbkt) {
    __shared__ unsigned ebuf[EBUF];     // 24 KB
    __shared__ unsigned lhist[256];
    __shared__ unsigned loffx[256];     // exclusive per-dst offsets
    __shared__ unsigned lcur[256];
    int b = blockIdx.x, t = threadIdx.x;
    unsigned lo = bstart[b], hi = bstart[b + 1];
    int cnt = (int)(hi - lo);
    int d0 = b << 8;
    int nd = min(N - d0, 256);
    bool fits = (cnt <= EBUF);

    lhist[t] = 0;
    lcur[t]  = 0;
    __syncthreads();

    if (fits) {
        for (int i = t; i < cnt; i += 256) {
            unsigned e = binned[lo + i];
            ebuf[i] = e;
            atomicAdd(&lhist[e >> 24], 1u);
        }
    } else {
        for (int i = t; i < cnt; i += 256)
            atomicAdd(&lhist[binned[lo + i] >> 24], 1u);
    }
    __syncthreads();

    // exclusive scan of lhist (Hillis-Steele over 256)
    unsigned v = lhist[t];
    loffx[t] = v;
    __syncthreads();
    for (int off = 1; off < 256; off <<= 1) {
        unsigned u = (t >= off) ? loffx[t - off] : 0u;
        __syncthreads();
        loffx[t] += u;
        __syncthreads();
    }
    unsigned excl = loffx[t] - v;
    __syncthreads();
    loffx[t] = excl;
    __syncthreads();

    if (t < nd) offsets[d0 + t] = lo + excl;
    if (b == nbkt - 1 && t == 0) offsets[N] = (unsigned)E;

    if (fits) {
        for (int i = t; i < cnt; i += 256) {
            unsigned e = ebuf[i];
            int ld = (int)(e >> 24);
            unsigned pos = loffx[ld] + atomicAdd(&lcur[ld], 1u);
            csr[lo + pos] = e & 0xFFFFFFu;
        }
    } else {
        for (int i = t; i < cnt; i += 256) {
            unsigned e = binned[lo + i];
            int ld = (int)(e >> 24);
            unsigned pos = loffx[ld] + atomicAdd(&lcur[ld], 1u);
            csr[lo + pos] = e & 0xFFFFFFu;
        }
    }
}

// ---------------------------------------------------------------------------
// Fused attention + aggregation. One 64-lane wave per node (4 nodes/block).
// 16 lanes per edge; z AND dz rows in FP16 (256 B/row, one uint4/lane).
// ---------------------------------------------------------------------------
__global__ __launch_bounds__(256) void k_node(
        const unsigned short* __restrict__ z_h, const unsigned short* __restrict__ dz_h,
        const unsigned* __restrict__ offsets, const unsigned* __restrict__ csr,
        float* __restrict__ out, int N) {
    int lane = threadIdx.x & 63;
    int wv   = threadIdx.x >> 6;          // 0..3
    int g    = lane >> 4;                 // edge slot 0..3
    int l16  = lane & 15;                 // row chunk: dims [8*l16, 8*l16+8)
    int n = blockIdx.x * 4 + wv;
    if (n >= N) return;

    unsigned start = offsets[n];
    int deg = (int)(offsets[n + 1] - start);
    float4* orow = (float4*)(out + (size_t)n * OUT_DIM);
    if (deg == 0) {
        if (g == 0) {
            orow[2 * l16]     = make_float4(0.f, 0.f, 0.f, 0.f);
            orow[2 * l16 + 1] = make_float4(0.f, 0.f, 0.f, 0.f);
        }
        return;
    }

    uint4 dq = ((const uint4*)(dz_h + (size_t)n * OUT_DIM))[l16];  // 8 fp16 dims

    float a[8];
#pragma unroll
    for (int k = 0; k < 8; ++k) a[k] = 0.f;
    float denom = 0.f;

    for (int i = 0; i < deg; i += 8) {
        int eA = i + g;
        int eB = i + 4 + g;
        bool vA = eA < deg;
        bool vB = eB < deg;
        int sA = vA ? (int)csr[start + eA] : 0;
        int sB = vB ? (int)csr[start + eB] : 0;
        uint4 qA = ((const uint4*)(z_h + (size_t)sA * OUT_DIM))[l16];
        uint4 qB = ((const uint4*)(z_h + (size_t)sB * OUT_DIM))[l16];

        float pA = dot2(qA.w, dq.w, dot2(qA.z, dq.z, dot2(qA.y, dq.y, dot2(qA.x, dq.x, 0.f))));
        float pB = dot2(qB.w, dq.w, dot2(qB.z, dq.z, dot2(qB.y, dq.y, dot2(qB.x, dq.x, 0.f))));
#pragma unroll
        for (int off = 1; off <= 8; off <<= 1) {   // reduce within 16-lane group
            pA += __shfl_xor(pA, off);
            pB += __shfl_xor(pB, off);
        }
        float wA = vA ? __expf(pA) : 0.f;
        float wB = vB ? __expf(pB) : 0.f;
        denom += wA + wB;

        float2 zA01 = h2f2(qA.x), zA23 = h2f2(qA.y), zA45 = h2f2(qA.z), zA67 = h2f2(qA.w);
        float2 zB01 = h2f2(qB.x), zB23 = h2f2(qB.y), zB45 = h2f2(qB.z), zB67 = h2f2(qB.w);
        a[0] += wA * zA01.x + wB * zB01.x;  a[1] += wA * zA01.y + wB * zB01.y;
        a[2] += wA * zA23.x + wB * zB23.x;  a[3] += wA * zA23.y + wB * zB23.y;
        a[4] += wA * zA45.x + wB * zB45.x;  a[5] += wA * zA45.y + wB * zB45.y;
        a[6] += wA * zA67.x + wB * zB67.x;  a[7] += wA * zA67.y + wB * zB67.y;
    }

    // fold the 4 edge-groups together (lanes l, l^16, l^32, l^48)
#pragma unroll
    for (int off = 16; off <= 32; off <<= 1) {
#pragma unroll
        for (int k = 0; k < 8; ++k) a[k] += __shfl_xor(a[k], off);
        denom += __shfl_xor(denom, off);
    }

    if (g == 0) {
        float inv = 1.f / denom;
        orow[2 * l16]     = make_float4(a[0] * inv, a[1] * inv, a[2] * inv, a[3] * inv);
        orow[2 * l16 + 1] = make_float4(a[4] * inv, a[5] * inv, a[6] * inv, a[7] * inv);
    }
}

// ---------------------------------------------------------------------------
extern "C" void kernel_launch(void* const* d_in, const int* in_sizes, int n_in,
                              void* d_out, int out_size, void* d_ws, size_t ws_size,
                              hipStream_t stream) {
    const float* h    = (const float*)d_in[0];
    const float* feat = (const float*)d_in[1];
    const float* Wfc  = (const float*)d_in[2];
    const float* Wdst = (const float*)d_in[3];
    const int*   src  = (const int*)d_in[4];
    const int*   dst  = (const int*)d_in[5];
    float*       out  = (float*)d_out;

    int N = in_sizes[0] / IN_DIM;
    int E = in_sizes[4];

    char* ws = (char*)d_ws;
    unsigned short* z_h  = (unsigned short*)ws; ws += (size_t)N * OUT_DIM * sizeof(unsigned short);
    unsigned short* dz_h = (unsigned short*)ws; ws += (size_t)N * OUT_DIM * sizeof(unsigned short);
    unsigned* Wfp      = (unsigned*)ws; ws += (size_t)8192 * sizeof(unsigned);
    unsigned* Wdp      = (unsigned*)ws; ws += (size_t)4096 * sizeof(unsigned);
    unsigned* binned   = (unsigned*)ws; ws += (size_t)E * sizeof(unsigned);
    unsigned* bcounts  = (unsigned*)ws; ws += (size_t)256 * sizeof(unsigned);
    unsigned* bstart   = (unsigned*)ws; ws += (size_t)260 * sizeof(unsigned);
    unsigned* bcursor  = (unsigned*)ws; ws += (size_t)256 * sizeof(unsigned);
    unsigned* offsets  = (unsigned*)ws; ws += (size_t)(N + 1) * sizeof(unsigned);
    unsigned* csr      = (unsigned*)ws;

    int nbz  = (N + NB - 1) / NB;        // 782
    int nbkt = (N + 255) / 256;          // 196 buckets

    k_wt     <<<48, 256, 0, stream>>>(Wfc, Wdst, Wfp, Wdp, bcounts);
    k_linear <<<2 * nbz, 256, 0, stream>>>(h, feat, Wfp, Wdp, z_h, dz_h, N, nbz);
    k_bhist  <<<512, 256, 0, stream>>>(dst, bcounts, E, nbkt);
    k_bscan  <<<1, 256, 0, stream>>>(bcounts, bstart, bcursor, nbkt);
    k_bin    <<<512, 256, 0, stream>>>(dst, src, bcursor, binned, E, nbkt);
    k_sortx  <<<nbkt, 256, 0, stream>>>(binned, bstart, offsets, csr, N, E, nbkt);
    k_node   <<<(N + 3) / 4, 256, 0, stream>>>(z_h, dz_h, offsets, csr, out, N);
}

// Round 19
// 111.931 us; speedup vs baseline: 1.3639x; 1.1025x over previous
//
#include <hip/hip_runtime.h>
#include <hip/hip_fp16.h>
#include <math.h>

#define IN_DIM   128
#define OUT_DIM  128
#define FEAT_DIM 64
#define NB       64     // nodes per k_linear block
#define NHB      512    // histogram blocks fused into k_linear's grid
#define EBUF     6144   // k_sortx LDS staging capacity (bucket mean 4083, 23 sigma)

typedef _Float16 h2v __attribute__((ext_vector_type(2)));

__device__ __forceinline__ float2 h2f2(unsigned u) {
    __half2 h = *reinterpret_cast<const __half2*>(&u);
    return __half22float2(h);
}
__device__ __forceinline__ unsigned f2h2(float a, float b) {
    __half2 h = __floats2half2_rn(a, b);
    return *reinterpret_cast<unsigned*>(&h);
}
// c += dot(half2 a, half2 b) with fp32 accumulate (V_DOT2_F32_F16)
__device__ __forceinline__ float dot2(unsigned a, unsigned b, float c) {
#if __has_builtin(__builtin_amdgcn_fdot2)
    return __builtin_amdgcn_fdot2(*reinterpret_cast<h2v*>(&a),
                                  *reinterpret_cast<h2v*>(&b), c, false);
#else
    float2 fa = h2f2(a), fb = h2f2(b);
    return c + fa.x * fb.x + fa.y * fb.y;
#endif
}

// ---------------------------------------------------------------------------
// k_wt: pack W_fc / W_dst as fp16 k-pairs; zero bcounts + breserve (512 words).
// ---------------------------------------------------------------------------
__global__ __launch_bounds__(256) void k_wt(const float* __restrict__ Wfc,
                                            const float* __restrict__ Wdst,
                                            unsigned* __restrict__ Wfp,
                                            unsigned* __restrict__ Wdp,
                                            unsigned* __restrict__ bzero) {
    int idx = blockIdx.x * 256 + threadIdx.x;       // 48 blocks = 12288 threads
    if (idx < 8192) {               // 64 k2 x 128 c
        int k2 = idx >> 7, c = idx & 127;
        Wfp[idx] = f2h2(Wfc[(2 * k2) * 128 + c], Wfc[(2 * k2 + 1) * 128 + c]);
    } else if (idx < 12288) {       // 32 k2 x 128 c
        int i2 = idx - 8192;
        int k2 = i2 >> 7, c = i2 & 127;
        Wdp[i2] = f2h2(Wdst[(2 * k2) * 128 + c], Wdst[(2 * k2 + 1) * 128 + c]);
    }
    if (idx < 512) bzero[idx] = 0u;   // bcounts[256] + breserve[256]
}

// ---------------------------------------------------------------------------
// k_fused: grid = 2*nbz + NHB.
//  [0,nbz)        : z  = fp16(h @ W_fc)     (v_dot2_f32_f16)
//  [nbz,2nbz)     : dz = fp16(feat @ W_dst) (v_dot2_f32_f16)
//  [2nbz,2nbz+NHB): bucket histogram of dst>>8 (LDS-aggregated, 196 counters)
// Histogram blocks overlap the GEMM blocks; bucket-level atomics only
// (NOT the r15 per-dst scatter-tail pattern).
// ---------------------------------------------------------------------------
__global__ __launch_bounds__(256) void k_fused(
        const float* __restrict__ h, const float* __restrict__ feat,
        const unsigned* __restrict__ Wfp, const unsigned* __restrict__ Wdp,
        unsigned short* __restrict__ z_h, unsigned short* __restrict__ dz_h,
        int N, int nbz,
        const int* __restrict__ dst, unsigned* __restrict__ bcounts, int E, int nbkt) {
    int t  = threadIdx.x;        // 0..255
    int b  = blockIdx.x;

    __shared__ uint2 sh[NB * 32];   // 16 KB (GEMM tiles); reused as histogram

    if (b >= 2 * nbz) {
        // ---- bucket histogram partition ----
        unsigned* hist = (unsigned*)sh;
        int hb = b - 2 * nbz;
        hist[t] = 0;
        __syncthreads();
        for (int i = hb * 256 + t; i < E; i += NHB * 256)
            atomicAdd(&hist[dst[i] >> 8], 1u);
        __syncthreads();
        if (t < nbkt && hist[t]) atomicAdd(&bcounts[t], hist[t]);
        return;
    }

    int c  = t & 31;             // cols 4c..4c+3
    int j0 = t >> 5;             // 0..7 -> nodes n0 + 8*j0 + jj
    bool do_z = (b < nbz);
    int n0 = (do_z ? b : b - nbz) * NB;

    float4 acc[8];
#pragma unroll
    for (int jj = 0; jj < 8; ++jj) acc[jj] = make_float4(0.f, 0.f, 0.f, 0.f);

    if (do_z) {
        for (int i = t; i < NB * 32; i += 256) {
            int row = i >> 5, col = i & 31;
            int n = min(n0 + row, N - 1);
            float4 v = ((const float4*)(h + (size_t)n * IN_DIM))[col];
            sh[i] = make_uint2(f2h2(v.x, v.y), f2h2(v.z, v.w));
        }
        __syncthreads();

        const uint4* Wp4 = (const uint4*)Wfp;   // [k2][32] uint4
#pragma unroll 2
        for (int k4 = 0; k4 < 32; ++k4) {
            uint4 wA = Wp4[(size_t)(2 * k4) * 32 + c];
            uint4 wB = Wp4[(size_t)(2 * k4 + 1) * 32 + c];
#pragma unroll
            for (int jj = 0; jj < 8; ++jj) {
                uint2 q = sh[(j0 * 8 + jj) * 32 + k4];
                acc[jj].x = dot2(q.y, wB.x, dot2(q.x, wA.x, acc[jj].x));
                acc[jj].y = dot2(q.y, wB.y, dot2(q.x, wA.y, acc[jj].y));
                acc[jj].z = dot2(q.y, wB.z, dot2(q.x, wA.z, acc[jj].z));
                acc[jj].w = dot2(q.y, wB.w, dot2(q.x, wA.w, acc[jj].w));
            }
        }
#pragma unroll
        for (int jj = 0; jj < 8; ++jj) {
            int n = n0 + j0 * 8 + jj;
            if (n < N) {
                uint2 pk = make_uint2(f2h2(acc[jj].x, acc[jj].y),
                                      f2h2(acc[jj].z, acc[jj].w));
                ((uint2*)(z_h + (size_t)n * OUT_DIM))[c] = pk;
            }
        }
    } else {
        for (int i = t; i < NB * 16; i += 256) {
            int row = i >> 4, col = i & 15;
            int n = min(n0 + row, N - 1);
            float4 v = ((const float4*)(feat + (size_t)n * FEAT_DIM))[col];
            sh[i] = make_uint2(f2h2(v.x, v.y), f2h2(v.z, v.w));
        }
        __syncthreads();

        const uint4* Wd4 = (const uint4*)Wdp;   // [k2][32] uint4
#pragma unroll 2
        for (int k4 = 0; k4 < 16; ++k4) {
            uint4 wA = Wd4[(size_t)(2 * k4) * 32 + c];
            uint4 wB = Wd4[(size_t)(2 * k4 + 1) * 32 + c];
#pragma unroll
            for (int jj = 0; jj < 8; ++jj) {
                uint2 q = sh[(j0 * 8 + jj) * 16 + k4];
                acc[jj].x = dot2(q.y, wB.x, dot2(q.x, wA.x, acc[jj].x));
                acc[jj].y = dot2(q.y, wB.y, dot2(q.x, wA.y, acc[jj].y));
                acc[jj].z = dot2(q.y, wB.z, dot2(q.x, wA.z, acc[jj].z));
                acc[jj].w = dot2(q.y, wB.w, dot2(q.x, wA.w, acc[jj].w));
            }
        }
#pragma unroll
        for (int jj = 0; jj < 8; ++jj) {
            int n = n0 + j0 * 8 + jj;
            if (n < N) {
                uint2 pk = make_uint2(f2h2(acc[jj].x, acc[jj].y),
                                      f2h2(acc[jj].z, acc[jj].w));
                ((uint2*)(dz_h + (size_t)n * OUT_DIM))[c] = pk;
            }
        }
    }
}

// ---------------------------------------------------------------------------
// k_bin: bin edges by bucket (dst>>8).  Each block computes the 196-bucket
// exclusive scan locally from bcounts (no k_bscan kernel), reserves space in
// its buckets via breserve, writes payload = src | local_dst<<24 grouped.
// ---------------------------------------------------------------------------
__global__ __launch_bounds__(256) void k_bin(
        const int* __restrict__ dst, const int* __restrict__ src,
        const unsigned* __restrict__ bcounts, unsigned* __restrict__ breserve,
        unsigned* __restrict__ binned, int E, int nbkt) {
    __shared__ unsigned bst[256];     // exclusive bucket starts
    __shared__ unsigned hist[256];
    __shared__ unsigned base[256];
    __shared__ unsigned cur[256];
    int t = threadIdx.x;

    // local exclusive scan of bcounts
    unsigned v = (t < nbkt) ? bcounts[t] : 0u;
    bst[t] = v;
    __syncthreads();
    for (int off = 1; off < 256; off <<= 1) {
        unsigned u = (t >= off) ? bst[t - off] : 0u;
        __syncthreads();
        bst[t] += u;
        __syncthreads();
    }
    unsigned excl = bst[t] - v;
    __syncthreads();
    bst[t] = excl;
    hist[t] = 0;
    cur[t]  = 0;
    __syncthreads();

    int per = (E + gridDim.x - 1) / gridDim.x;
    int lo = blockIdx.x * per;
    int hi = min(E, lo + per);

    for (int i = lo + t; i < hi; i += 256)
        atomicAdd(&hist[dst[i] >> 8], 1u);
    __syncthreads();
    if (t < nbkt && hist[t]) base[t] = bst[t] + atomicAdd(&breserve[t], hist[t]);
    __syncthreads();
    for (int i = lo + t; i < hi; i += 256) {
        int d = dst[i];
        int bk = d >> 8;
        unsigned slot = base[bk] + atomicAdd(&cur[bk], 1u);
        binned[slot] = (unsigned)src[i] | ((unsigned)(d & 255) << 24);
    }
}

// ---------------------------------------------------------------------------
// k_sortx: block b owns bucket b.  Local scan of bcounts -> bucket window;
// stage bucket edges in LDS, per-dst LDS histogram + scan -> offsets + csr.
// ---------------------------------------------------------------------------
__global__ __launch_bounds__(256) void k_sortx(
        const unsigned* __restrict__ binned, const unsigned* __restrict__ bcounts,
        unsigned* __restrict__ offsets, unsigned* __restrict__ csr,
        int N, int E, int nbkt) {
    __shared__ unsigned ebuf[EBUF];     // 24 KB
    __shared__ unsigned bst[256];
    __shared__ unsigned lhist[256];
    __shared__ unsigned loffx[256];     // exclusive per-dst offsets
    __shared__ unsigned lcur[256];
    int b = blockIdx.x, t = threadIdx.x;

    // local exclusive scan of bcounts for this block's window
    unsigned v = (t < nbkt) ? bcounts[t] : 0u;
    bst[t] = v;
    __syncthreads();
    for (int off = 1; off < 256; off <<= 1) {
        unsigned u = (t >= off) ? bst[t - off] : 0u;
        __syncthreads();
        bst[t] += u;
        __syncthreads();
    }
    unsigned excl = bst[t] - v;
    __syncthreads();
    bst[t] = excl;
    lhist[t] = 0;
    lcur[t]  = 0;
    __syncthreads();

    unsigned lo = bst[b];
    int cnt = (int)((b < nbkt) ? bcounts[b] : 0u);
    int d0 = b << 8;
    int nd = min(N - d0, 256);
    bool fits = (cnt <= EBUF);

    if (fits) {
        for (int i = t; i < cnt; i += 256) {
            unsigned e = binned[lo + i];
            ebuf[i] = e;
            atomicAdd(&lhist[e >> 24], 1u);
        }
    } else {
        for (int i = t; i < cnt; i += 256)
            atomicAdd(&lhist[binned[lo + i] >> 24], 1u);
    }
    __syncthreads();

    // exclusive scan of lhist
    unsigned lv = lhist[t];
    loffx[t] = lv;
    __syncthreads();
    for (int off = 1; off < 256; off <<= 1) {
        unsigned u = (t >= off) ? loffx[t - off] : 0u;
        __syncthreads();
        loffx[t] += u;
        __syncthreads();
    }
    unsigned lexcl = loffx[t] - lv;
    __syncthreads();
    loffx[t] = lexcl;
    __syncthreads();

    if (t < nd) offsets[d0 + t] = lo + lexcl;
    if (b == nbkt - 1 && t == 0) offsets[N] = (unsigned)E;

    if (fits) {
        for (int i = t; i < cnt; i += 256) {
            unsigned e = ebuf[i];
            int ld = (int)(e >> 24);
            unsigned pos = loffx[ld] + atomicAdd(&lcur[ld], 1u);
            csr[lo + pos] = e & 0xFFFFFFu;
        }
    } else {
        for (int i = t; i < cnt; i += 256) {
            unsigned e = binned[lo + i];
            int ld = (int)(e >> 24);
            unsigned pos = loffx[ld] + atomicAdd(&lcur[ld], 1u);
            csr[lo + pos] = e & 0xFFFFFFu;
        }
    }
}

// ---------------------------------------------------------------------------
// Fused attention + aggregation. One 64-lane wave per node (4 nodes/block).
// 16 lanes per edge; z AND dz rows in FP16 (256 B/row, one uint4/lane).
// ---------------------------------------------------------------------------
__global__ __launch_bounds__(256) void k_node(
        const unsigned short* __restrict__ z_h, const unsigned short* __restrict__ dz_h,
        const unsigned* __restrict__ offsets, const unsigned* __restrict__ csr,
        float* __restrict__ out, int N) {
    int lane = threadIdx.x & 63;
    int wv   = threadIdx.x >> 6;          // 0..3
    int g    = lane >> 4;                 // edge slot 0..3
    int l16  = lane & 15;                 // row chunk: dims [8*l16, 8*l16+8)
    int n = blockIdx.x * 4 + wv;
    if (n >= N) return;

    unsigned start = offsets[n];
    int deg = (int)(offsets[n + 1] - start);
    float4* orow = (float4*)(out + (size_t)n * OUT_DIM);
    if (deg == 0) {
        if (g == 0) {
            orow[2 * l16]     = make_float4(0.f, 0.f, 0.f, 0.f);
            orow[2 * l16 + 1] = make_float4(0.f, 0.f, 0.f, 0.f);
        }
        return;
    }

    uint4 dq = ((const uint4*)(dz_h + (size_t)n * OUT_DIM))[l16];  // 8 fp16 dims

    float a[8];
#pragma unroll
    for (int k = 0; k < 8; ++k) a[k] = 0.f;
    float denom = 0.f;

    for (int i = 0; i < deg; i += 8) {
        int eA = i + g;
        int eB = i + 4 + g;
        bool vA = eA < deg;
        bool vB = eB < deg;
        int sA = vA ? (int)csr[start + eA] : 0;
        int sB = vB ? (int)csr[start + eB] : 0;
        uint4 qA = ((const uint4*)(z_h + (size_t)sA * OUT_DIM))[l16];
        uint4 qB = ((const uint4*)(z_h + (size_t)sB * OUT_DIM))[l16];

        float pA = dot2(qA.w, dq.w, dot2(qA.z, dq.z, dot2(qA.y, dq.y, dot2(qA.x, dq.x, 0.f))));
        float pB = dot2(qB.w, dq.w, dot2(qB.z, dq.z, dot2(qB.y, dq.y, dot2(qB.x, dq.x, 0.f))));
#pragma unroll
        for (int off = 1; off <= 8; off <<= 1) {   // reduce within 16-lane group
            pA += __shfl_xor(pA, off);
            pB += __shfl_xor(pB, off);
        }
        float wA = vA ? __expf(pA) : 0.f;
        float wB = vB ? __expf(pB) : 0.f;
        denom += wA + wB;

        float2 zA01 = h2f2(qA.x), zA23 = h2f2(qA.y), zA45 = h2f2(qA.z), zA67 = h2f2(qA.w);
        float2 zB01 = h2f2(qB.x), zB23 = h2f2(qB.y), zB45 = h2f2(qB.z), zB67 = h2f2(qB.w);
        a[0] += wA * zA01.x + wB * zB01.x;  a[1] += wA * zA01.y + wB * zB01.y;
        a[2] += wA * zA23.x + wB * zB23.x;  a[3] += wA * zA23.y + wB * zB23.y;
        a[4] += wA * zA45.x + wB * zB45.x;  a[5] += wA * zA45.y + wB * zB45.y;
        a[6] += wA * zA67.x + wB * zB67.x;  a[7] += wA * zA67.y + wB * zB67.y;
    }

    // fold the 4 edge-groups together (lanes l, l^16, l^32, l^48)
#pragma unroll
    for (int off = 16; off <= 32; off <<= 1) {
#pragma unroll
        for (int k = 0; k < 8; ++k) a[k] += __shfl_xor(a[k], off);
        denom += __shfl_xor(denom, off);
    }

    if (g == 0) {
        float inv = 1.f / denom;
        orow[2 * l16]     = make_float4(a[0] * inv, a[1] * inv, a[2] * inv, a[3] * inv);
        orow[2 * l16 + 1] = make_float4(a[4] * inv, a[5] * inv, a[6] * inv, a[7] * inv);
    }
}

// ---------------------------------------------------------------------------
extern "C" void kernel_launch(void* const* d_in, const int* in_sizes, int n_in,
                              void* d_out, int out_size, void* d_ws, size_t ws_size,
                              hipStream_t stream) {
    const float* h    = (const float*)d_in[0];
    const float* feat = (const float*)d_in[1];
    const float* Wfc  = (const float*)d_in[2];
    const float* Wdst = (const float*)d_in[3];
    const int*   src  = (const int*)d_in[4];
    const int*   dst  = (const int*)d_in[5];
    float*       out  = (float*)d_out;

    int N = in_sizes[0] / IN_DIM;
    int E = in_sizes[4];

    char* ws = (char*)d_ws;
    unsigned short* z_h  = (unsigned short*)ws; ws += (size_t)N * OUT_DIM * sizeof(unsigned short);
    unsigned short* dz_h = (unsigned short*)ws; ws += (size_t)N * OUT_DIM * sizeof(unsigned short);
    unsigned* Wfp      = (unsigned*)ws; ws += (size_t)8192 * sizeof(unsigned);
    unsigned* Wdp      = (unsigned*)ws; ws += (size_t)4096 * sizeof(unsigned);
    unsigned* binned   = (unsigned*)ws; ws += (size_t)E * sizeof(unsigned);
    unsigned* bcounts  = (unsigned*)ws; ws += (size_t)256 * sizeof(unsigned);
    unsigned* breserve = (unsigned*)ws; ws += (size_t)256 * sizeof(unsigned);
    unsigned* offsets  = (unsigned*)ws; ws += (size_t)(N + 1) * sizeof(unsigned);
    unsigned* csr      = (unsigned*)ws;

    int nbz  = (N + NB - 1) / NB;        // 782
    int nbkt = (N + 255) / 256;          // 196 buckets

    k_wt    <<<48, 256, 0, stream>>>(Wfc, Wdst, Wfp, Wdp, bcounts);  // bcounts+breserve adjacent
    k_fused <<<2 * nbz + NHB, 256, 0, stream>>>(h, feat, Wfp, Wdp, z_h, dz_h,
                                                N, nbz, dst, bcounts, E, nbkt);
    k_bin   <<<512, 256, 0, stream>>>(dst, src, bcounts, breserve, binned, E, nbkt);
    k_sortx <<<nbkt, 256, 0, stream>>>(binned, bcounts, offsets, csr, N, E, nbkt);
    k_node  <<<(N + 3) / 4, 256, 0, stream>>>(z_h, dz_h, offsets, csr, out, N);
}

// Round 20
// 111.882 us; speedup vs baseline: 1.3645x; 1.0004x over previous
//
#include <hip/hip_runtime.h>
#include <hip/hip_fp16.h>
#include <math.h>

#define IN_DIM   128
#define OUT_DIM  128
#define FEAT_DIM 64
#define NB       64     // nodes per k_linear block
#define NHB      512    // histogram blocks fused into k_fused's grid
#define EBUF     6144   // k_sortx LDS staging capacity (bucket mean 4083, 23 sigma)

typedef _Float16 h2v __attribute__((ext_vector_type(2)));

__device__ __forceinline__ float2 h2f2(unsigned u) {
    __half2 h = *reinterpret_cast<const __half2*>(&u);
    return __half22float2(h);
}
__device__ __forceinline__ unsigned f2h2(float a, float b) {
    __half2 h = __floats2half2_rn(a, b);
    return *reinterpret_cast<unsigned*>(&h);
}
// c += dot(half2 a, half2 b) with fp32 accumulate (V_DOT2_F32_F16)
__device__ __forceinline__ float dot2(unsigned a, unsigned b, float c) {
#if __has_builtin(__builtin_amdgcn_fdot2)
    return __builtin_amdgcn_fdot2(*reinterpret_cast<h2v*>(&a),
                                  *reinterpret_cast<h2v*>(&b), c, false);
#else
    float2 fa = h2f2(a), fb = h2f2(b);
    return c + fa.x * fb.x + fa.y * fb.y;
#endif
}

// ---------------------------------------------------------------------------
// k_wt: pack W_fc / W_dst as fp16 k-pairs; zero bcounts + breserve (512 words).
// ---------------------------------------------------------------------------
__global__ __launch_bounds__(256) void k_wt(const float* __restrict__ Wfc,
                                            const float* __restrict__ Wdst,
                                            unsigned* __restrict__ Wfp,
                                            unsigned* __restrict__ Wdp,
                                            unsigned* __restrict__ bzero) {
    int idx = blockIdx.x * 256 + threadIdx.x;       // 48 blocks = 12288 threads
    if (idx < 8192) {               // 64 k2 x 128 c
        int k2 = idx >> 7, c = idx & 127;
        Wfp[idx] = f2h2(Wfc[(2 * k2) * 128 + c], Wfc[(2 * k2 + 1) * 128 + c]);
    } else if (idx < 12288) {       // 32 k2 x 128 c
        int i2 = idx - 8192;
        int k2 = i2 >> 7, c = i2 & 127;
        Wdp[i2] = f2h2(Wdst[(2 * k2) * 128 + c], Wdst[(2 * k2 + 1) * 128 + c]);
    }
    if (idx < 512) bzero[idx] = 0u;   // bcounts[256] + breserve[256]
}

// ---------------------------------------------------------------------------
// k_fused: grid = 2*nbz + NHB.
//  [0,nbz)        : z  = fp16(h @ W_fc)     (v_dot2_f32_f16)
//  [nbz,2nbz)     : dz = fp16(feat @ W_dst) (v_dot2_f32_f16)
//  [2nbz,2nbz+NHB): bucket histogram of dst>>8 (LDS-aggregated, 196 counters)
// GEMM thread tiling: 4 nodes x 8 cols per thread (chunks c and c+16) —
// halves LDS bytes per dot2 vs 8x4 (LDS pipe shared by 4 SIMDs was the
// r19 co-limiter), and wave LDS reads become 4-address broadcasts.
// ---------------------------------------------------------------------------
__global__ __launch_bounds__(256) void k_fused(
        const float* __restrict__ h, const float* __restrict__ feat,
        const unsigned* __restrict__ Wfp, const unsigned* __restrict__ Wdp,
        unsigned short* __restrict__ z_h, unsigned short* __restrict__ dz_h,
        int N, int nbz,
        const int* __restrict__ dst, unsigned* __restrict__ bcounts, int E, int nbkt) {
    int t  = threadIdx.x;        // 0..255
    int b  = blockIdx.x;

    __shared__ uint2 sh[NB * 32];   // 16 KB (GEMM tiles); reused as histogram

    if (b >= 2 * nbz) {
        // ---- bucket histogram partition ----
        unsigned* hist = (unsigned*)sh;
        int hb = b - 2 * nbz;
        hist[t] = 0;
        __syncthreads();
        for (int i = hb * 256 + t; i < E; i += NHB * 256)
            atomicAdd(&hist[dst[i] >> 8], 1u);
        __syncthreads();
        if (t < nbkt && hist[t]) atomicAdd(&bcounts[t], hist[t]);
        return;
    }

    int c  = t & 15;             // col chunks c and c+16 (cols 4c..4c+3, 4c+64..4c+67)
    int j0 = t >> 4;             // 0..15 -> nodes n0 + 4*j0 + jj (jj<4)
    bool do_z = (b < nbz);
    int n0 = (do_z ? b : b - nbz) * NB;

    float4 accA[4], accB[4];
#pragma unroll
    for (int jj = 0; jj < 4; ++jj) {
        accA[jj] = make_float4(0.f, 0.f, 0.f, 0.f);
        accB[jj] = make_float4(0.f, 0.f, 0.f, 0.f);
    }

    if (do_z) {
        // stage h tile fp16: [node][32] uint2 (uint2 = 2 k-pairs = 4 k)
        for (int i = t; i < NB * 32; i += 256) {
            int row = i >> 5, col = i & 31;
            int n = min(n0 + row, N - 1);
            float4 v = ((const float4*)(h + (size_t)n * IN_DIM))[col];
            sh[i] = make_uint2(f2h2(v.x, v.y), f2h2(v.z, v.w));
        }
        __syncthreads();

        const uint4* Wp4 = (const uint4*)Wfp;   // [k2][32] uint4
#pragma unroll 2
        for (int k4 = 0; k4 < 32; ++k4) {
            uint4 wA0 = Wp4[(size_t)(2 * k4) * 32 + c];
            uint4 wA1 = Wp4[(size_t)(2 * k4) * 32 + c + 16];
            uint4 wB0 = Wp4[(size_t)(2 * k4 + 1) * 32 + c];
            uint4 wB1 = Wp4[(size_t)(2 * k4 + 1) * 32 + c + 16];
#pragma unroll
            for (int jj = 0; jj < 4; ++jj) {
                uint2 q = sh[(j0 * 4 + jj) * 32 + k4];
                accA[jj].x = dot2(q.y, wB0.x, dot2(q.x, wA0.x, accA[jj].x));
                accA[jj].y = dot2(q.y, wB0.y, dot2(q.x, wA0.y, accA[jj].y));
                accA[jj].z = dot2(q.y, wB0.z, dot2(q.x, wA0.z, accA[jj].z));
                accA[jj].w = dot2(q.y, wB0.w, dot2(q.x, wA0.w, accA[jj].w));
                accB[jj].x = dot2(q.y, wB1.x, dot2(q.x, wA1.x, accB[jj].x));
                accB[jj].y = dot2(q.y, wB1.y, dot2(q.x, wA1.y, accB[jj].y));
                accB[jj].z = dot2(q.y, wB1.z, dot2(q.x, wA1.z, accB[jj].z));
                accB[jj].w = dot2(q.y, wB1.w, dot2(q.x, wA1.w, accB[jj].w));
            }
        }
#pragma unroll
        for (int jj = 0; jj < 4; ++jj) {
            int n = n0 + j0 * 4 + jj;
            if (n < N) {
                uint2* zr = (uint2*)(z_h + (size_t)n * OUT_DIM);
                zr[c]      = make_uint2(f2h2(accA[jj].x, accA[jj].y),
                                        f2h2(accA[jj].z, accA[jj].w));
                zr[c + 16] = make_uint2(f2h2(accB[jj].x, accB[jj].y),
                                        f2h2(accB[jj].z, accB[jj].w));
            }
        }
    } else {
        // stage feat tile fp16: [node][16] uint2
        for (int i = t; i < NB * 16; i += 256) {
            int row = i >> 4, col = i & 15;
            int n = min(n0 + row, N - 1);
            float4 v = ((const float4*)(feat + (size_t)n * FEAT_DIM))[col];
            sh[i] = make_uint2(f2h2(v.x, v.y), f2h2(v.z, v.w));
        }
        __syncthreads();

        const uint4* Wd4 = (const uint4*)Wdp;   // [k2][32] uint4
#pragma unroll 2
        for (int k4 = 0; k4 < 16; ++k4) {
            uint4 wA0 = Wd4[(size_t)(2 * k4) * 32 + c];
            uint4 wA1 = Wd4[(size_t)(2 * k4) * 32 + c + 16];
            uint4 wB0 = Wd4[(size_t)(2 * k4 + 1) * 32 + c];
            uint4 wB1 = Wd4[(size_t)(2 * k4 + 1) * 32 + c + 16];
#pragma unroll
            for (int jj = 0; jj < 4; ++jj) {
                uint2 q = sh[(j0 * 4 + jj) * 16 + k4];
                accA[jj].x = dot2(q.y, wB0.x, dot2(q.x, wA0.x, accA[jj].x));
                accA[jj].y = dot2(q.y, wB0.y, dot2(q.x, wA0.y, accA[jj].y));
                accA[jj].z = dot2(q.y, wB0.z, dot2(q.x, wA0.z, accA[jj].z));
                accA[jj].w = dot2(q.y, wB0.w, dot2(q.x, wA0.w, accA[jj].w));
                accB[jj].x = dot2(q.y, wB1.x, dot2(q.x, wA1.x, accB[jj].x));
                accB[jj].y = dot2(q.y, wB1.y, dot2(q.x, wA1.y, accB[jj].y));
                accB[jj].z = dot2(q.y, wB1.z, dot2(q.x, wA1.z, accB[jj].z));
                accB[jj].w = dot2(q.y, wB1.w, dot2(q.x, wA1.w, accB[jj].w));
            }
        }
#pragma unroll
        for (int jj = 0; jj < 4; ++jj) {
            int n = n0 + j0 * 4 + jj;
            if (n < N) {
                uint2* dr = (uint2*)(dz_h + (size_t)n * OUT_DIM);
                dr[c]      = make_uint2(f2h2(accA[jj].x, accA[jj].y),
                                        f2h2(accA[jj].z, accA[jj].w));
                dr[c + 16] = make_uint2(f2h2(accB[jj].x, accB[jj].y),
                                        f2h2(accB[jj].z, accB[jj].w));
            }
        }
    }
}

// ---------------------------------------------------------------------------
// k_bin: bin edges by bucket (dst>>8).  Each block computes the 196-bucket
// exclusive scan locally from bcounts, reserves space via breserve, writes
// payload = src | local_dst<<24 grouped (line-filling).
// ---------------------------------------------------------------------------
__global__ __launch_bounds__(256) void k_bin(
        const int* __restrict__ dst, const int* __restrict__ src,
        const unsigned* __restrict__ bcounts, unsigned* __restrict__ breserve,
        unsigned* __restrict__ binned, int E, int nbkt) {
    __shared__ unsigned bst[256];     // exclusive bucket starts
    __shared__ unsigned hist[256];
    __shared__ unsigned base[256];
    __shared__ unsigned cur[256];
    int t = threadIdx.x;

    unsigned v = (t < nbkt) ? bcounts[t] : 0u;
    bst[t] = v;
    __syncthreads();
    for (int off = 1; off < 256; off <<= 1) {
        unsigned u = (t >= off) ? bst[t - off] : 0u;
        __syncthreads();
        bst[t] += u;
        __syncthreads();
    }
    unsigned excl = bst[t] - v;
    __syncthreads();
    bst[t] = excl;
    hist[t] = 0;
    cur[t]  = 0;
    __syncthreads();

    int per = (E + gridDim.x - 1) / gridDim.x;
    int lo = blockIdx.x * per;
    int hi = min(E, lo + per);

    for (int i = lo + t; i < hi; i += 256)
        atomicAdd(&hist[dst[i] >> 8], 1u);
    __syncthreads();
    if (t < nbkt && hist[t]) base[t] = bst[t] + atomicAdd(&breserve[t], hist[t]);
    __syncthreads();
    for (int i = lo + t; i < hi; i += 256) {
        int d = dst[i];
        int bk = d >> 8;
        unsigned slot = base[bk] + atomicAdd(&cur[bk], 1u);
        binned[slot] = (unsigned)src[i] | ((unsigned)(d & 255) << 24);
    }
}

// ---------------------------------------------------------------------------
// k_sortx: block b owns bucket b.  Local scan of bcounts -> bucket window;
// stage bucket edges in LDS, per-dst LDS histogram + scan -> offsets + csr.
// ---------------------------------------------------------------------------
__global__ __launch_bounds__(256) void k_sortx(
        const unsigned* __restrict__ binned, const unsigned* __restrict__ bcounts,
        unsigned* __restrict__ offsets, unsigned* __restrict__ csr,
        int N, int E, int nbkt) {
    __shared__ unsigned ebuf[EBUF];     // 24 KB
    __shared__ unsigned bst[256];
    __shared__ unsigned lhist[256];
    __shared__ unsigned loffx[256];     // exclusive per-dst offsets
    __shared__ unsigned lcur[256];
    int b = blockIdx.x, t = threadIdx.x;

    unsigned v = (t < nbkt) ? bcounts[t] : 0u;
    bst[t] = v;
    __syncthreads();
    for (int off = 1; off < 256; off <<= 1) {
        unsigned u = (t >= off) ? bst[t - off] : 0u;
        __syncthreads();
        bst[t] += u;
        __syncthreads();
    }
    unsigned excl = bst[t] - v;
    __syncthreads();
    bst[t] = excl;
    lhist[t] = 0;
    lcur[t]  = 0;
    __syncthreads();

    unsigned lo = bst[b];
    int cnt = (int)((b < nbkt) ? bcounts[b] : 0u);
    int d0 = b << 8;
    int nd = min(N - d0, 256);
    bool fits = (cnt <= EBUF);

    if (fits) {
        for (int i = t; i < cnt; i += 256) {
            unsigned e = binned[lo + i];
            ebuf[i] = e;
            atomicAdd(&lhist[e >> 24], 1u);
        }
    } else {
        for (int i = t; i < cnt; i += 256)
            atomicAdd(&lhist[binned[lo + i] >> 24], 1u);
    }
    __syncthreads();

    unsigned lv = lhist[t];
    loffx[t] = lv;
    __syncthreads();
    for (int off = 1; off < 256; off <<= 1) {
        unsigned u = (t >= off) ? loffx[t - off] : 0u;
        __syncthreads();
        loffx[t] += u;
        __syncthreads();
    }
    unsigned lexcl = loffx[t] - lv;
    __syncthreads();
    loffx[t] = lexcl;
    __syncthreads();

    if (t < nd) offsets[d0 + t] = lo + lexcl;
    if (b == nbkt - 1 && t == 0) offsets[N] = (unsigned)E;

    if (fits) {
        for (int i = t; i < cnt; i += 256) {
            unsigned e = ebuf[i];
            int ld = (int)(e >> 24);
            unsigned pos = loffx[ld] + atomicAdd(&lcur[ld], 1u);
            csr[lo + pos] = e & 0xFFFFFFu;
        }
    } else {
        for (int i = t; i < cnt; i += 256) {
            unsigned e = binned[lo + i];
            int ld = (int)(e >> 24);
            unsigned pos = loffx[ld] + atomicAdd(&lcur[ld], 1u);
            csr[lo + pos] = e & 0xFFFFFFu;
        }
    }
}

// ---------------------------------------------------------------------------
// Fused attention + aggregation. One 64-lane wave per node (4 nodes/block).
// 16 lanes per edge; z AND dz rows in FP16 (256 B/row, one uint4/lane).
// ---------------------------------------------------------------------------
__global__ __launch_bounds__(256) void k_node(
        const unsigned short* __restrict__ z_h, const unsigned short* __restrict__ dz_h,
        const unsigned* __restrict__ offsets, const unsigned* __restrict__ csr,
        float* __restrict__ out, int N) {
    int lane = threadIdx.x & 63;
    int wv   = threadIdx.x >> 6;          // 0..3
    int g    = lane >> 4;                 // edge slot 0..3
    int l16  = lane & 15;                 // row chunk: dims [8*l16, 8*l16+8)
    int n = blockIdx.x * 4 + wv;
    if (n >= N) return;

    unsigned start = offsets[n];
    int deg = (int)(offsets[n + 1] - start);
    float4* orow = (float4*)(out + (size_t)n * OUT_DIM);
    if (deg == 0) {
        if (g == 0) {
            orow[2 * l16]     = make_float4(0.f, 0.f, 0.f, 0.f);
            orow[2 * l16 + 1] = make_float4(0.f, 0.f, 0.f, 0.f);
        }
        return;
    }

    uint4 dq = ((const uint4*)(dz_h + (size_t)n * OUT_DIM))[l16];  // 8 fp16 dims

    float a[8];
#pragma unroll
    for (int k = 0; k < 8; ++k) a[k] = 0.f;
    float denom = 0.f;

    for (int i = 0; i < deg; i += 8) {
        int eA = i + g;
        int eB = i + 4 + g;
        bool vA = eA < deg;
        bool vB = eB < deg;
        int sA = vA ? (int)csr[start + eA] : 0;
        int sB = vB ? (int)csr[start + eB] : 0;
        uint4 qA = ((const uint4*)(z_h + (size_t)sA * OUT_DIM))[l16];
        uint4 qB = ((const uint4*)(z_h + (size_t)sB * OUT_DIM))[l16];

        float pA = dot2(qA.w, dq.w, dot2(qA.z, dq.z, dot2(qA.y, dq.y, dot2(qA.x, dq.x, 0.f))));
        float pB = dot2(qB.w, dq.w, dot2(qB.z, dq.z, dot2(qB.y, dq.y, dot2(qB.x, dq.x, 0.f))));
#pragma unroll
        for (int off = 1; off <= 8; off <<= 1) {   // reduce within 16-lane group
            pA += __shfl_xor(pA, off);
            pB += __shfl_xor(pB, off);
        }
        float wA = vA ? __expf(pA) : 0.f;
        float wB = vB ? __expf(pB) : 0.f;
        denom += wA + wB;

        float2 zA01 = h2f2(qA.x), zA23 = h2f2(qA.y), zA45 = h2f2(qA.z), zA67 = h2f2(qA.w);
        float2 zB01 = h2f2(qB.x), zB23 = h2f2(qB.y), zB45 = h2f2(qB.z), zB67 = h2f2(qB.w);
        a[0] += wA * zA01.x + wB * zB01.x;  a[1] += wA * zA01.y + wB * zB01.y;
        a[2] += wA * zA23.x + wB * zB23.x;  a[3] += wA * zA23.y + wB * zB23.y;
        a[4] += wA * zA45.x + wB * zB45.x;  a[5] += wA * zA45.y + wB * zB45.y;
        a[6] += wA * zA67.x + wB * zB67.x;  a[7] += wA * zA67.y + wB * zB67.y;
    }

    // fold the 4 edge-groups together (lanes l, l^16, l^32, l^48)
#pragma unroll
    for (int off = 16; off <= 32; off <<= 1) {
#pragma unroll
        for (int k = 0; k < 8; ++k) a[k] += __shfl_xor(a[k], off);
        denom += __shfl_xor(denom, off);
    }

    if (g == 0) {
        float inv = 1.f / denom;
        orow[2 * l16]     = make_float4(a[0] * inv, a[1] * inv, a[2] * inv, a[3] * inv);
        orow[2 * l16 + 1] = make_float4(a[4] * inv, a[5] * inv, a[6] * inv, a[7] * inv);
    }
}

// ---------------------------------------------------------------------------
extern "C" void kernel_launch(void* const* d_in, const int* in_sizes, int n_in,
                              void* d_out, int out_size, void* d_ws, size_t ws_size,
                              hipStream_t stream) {
    const float* h    = (const float*)d_in[0];
    const float* feat = (const float*)d_in[1];
    const float* Wfc  = (const float*)d_in[2];
    const float* Wdst = (const float*)d_in[3];
    const int*   src  = (const int*)d_in[4];
    const int*   dst  = (const int*)d_in[5];
    float*       out  = (float*)d_out;

    int N = in_sizes[0] / IN_DIM;
    int E = in_sizes[4];

    char* ws = (char*)d_ws;
    unsigned short* z_h  = (unsigned short*)ws; ws += (size_t)N * OUT_DIM * sizeof(unsigned short);
    unsigned short* dz_h = (unsigned short*)ws; ws += (size_t)N * OUT_DIM * sizeof(unsigned short);
    unsigned* Wfp      = (unsigned*)ws; ws += (size_t)8192 * sizeof(unsigned);
    unsigned* Wdp      = (unsigned*)ws; ws += (size_t)4096 * sizeof(unsigned);
    unsigned* binned   = (unsigned*)ws; ws += (size_t)E * sizeof(unsigned);
    unsigned* bcounts  = (unsigned*)ws; ws += (size_t)256 * sizeof(unsigned);
    unsigned* breserve = (unsigned*)ws; ws += (size_t)256 * sizeof(unsigned);
    unsigned* offsets  = (unsigned*)ws; ws += (size_t)(N + 1) * sizeof(unsigned);
    unsigned* csr      = (unsigned*)ws;

    int nbz  = (N + NB - 1) / NB;        // 782
    int nbkt = (N + 255) / 256;          // 196 buckets

    k_wt    <<<48, 256, 0, stream>>>(Wfc, Wdst, Wfp, Wdp, bcounts);  // bcounts+breserve adjacent
    k_fused <<<2 * nbz + NHB, 256, 0, stream>>>(h, feat, Wfp, Wdp, z_h, dz_h,
                                                N, nbz, dst, bcounts, E, nbkt);
    k_bin   <<<512, 256, 0, stream>>>(dst, src, bcounts, breserve, binned, E, nbkt);
    k_sortx <<<nbkt, 256, 0, stream>>>(binned, bcounts, offsets, csr, N, E, nbkt);
    k_node  <<<(N + 3) / 4, 256, 0, stream>>>(z_h, dz_h, offsets, csr, out, N);
}

// Round 21
// 111.396 us; speedup vs baseline: 1.3704x; 1.0044x over previous
//
#include <hip/hip_runtime.h>
#include <hip/hip_fp16.h>
#include <math.h>

#define IN_DIM   128
#define OUT_DIM  128
#define FEAT_DIM 64
#define NB       64     // nodes per k_linear block
#define NHB      512    // histogram blocks fused into k_fused's grid
#define EBUF     6144   // k_sortx LDS staging capacity (bucket mean 4083, 23 sigma)
#define HPAD     33     // padded h-tile row stride (uint2) — bank-conflict-free
#define FPAD     17     // padded feat-tile row stride (uint2)

typedef _Float16 h2v __attribute__((ext_vector_type(2)));

__device__ __forceinline__ float2 h2f2(unsigned u) {
    __half2 h = *reinterpret_cast<const __half2*>(&u);
    return __half22float2(h);
}
__device__ __forceinline__ unsigned f2h2(float a, float b) {
    __half2 h = __floats2half2_rn(a, b);
    return *reinterpret_cast<unsigned*>(&h);
}
// c += dot(half2 a, half2 b) with fp32 accumulate (V_DOT2_F32_F16)
__device__ __forceinline__ float dot2(unsigned a, unsigned b, float c) {
#if __has_builtin(__builtin_amdgcn_fdot2)
    return __builtin_amdgcn_fdot2(*reinterpret_cast<h2v*>(&a),
                                  *reinterpret_cast<h2v*>(&b), c, false);
#else
    float2 fa = h2f2(a), fb = h2f2(b);
    return c + fa.x * fb.x + fa.y * fb.y;
#endif
}

// ---------------------------------------------------------------------------
// k_wt: pack W_fc / W_dst as fp16 k-pairs; zero bcounts + breserve (512 words).
// ---------------------------------------------------------------------------
__global__ __launch_bounds__(256) void k_wt(const float* __restrict__ Wfc,
                                            const float* __restrict__ Wdst,
                                            unsigned* __restrict__ Wfp,
                                            unsigned* __restrict__ Wdp,
                                            unsigned* __restrict__ bzero) {
    int idx = blockIdx.x * 256 + threadIdx.x;       // 48 blocks = 12288 threads
    if (idx < 8192) {               // 64 k2 x 128 c
        int k2 = idx >> 7, c = idx & 127;
        Wfp[idx] = f2h2(Wfc[(2 * k2) * 128 + c], Wfc[(2 * k2 + 1) * 128 + c]);
    } else if (idx < 12288) {       // 32 k2 x 128 c
        int i2 = idx - 8192;
        int k2 = i2 >> 7, c = i2 & 127;
        Wdp[i2] = f2h2(Wdst[(2 * k2) * 128 + c], Wdst[(2 * k2 + 1) * 128 + c]);
    }
    if (idx < 512) bzero[idx] = 0u;   // bcounts[256] + breserve[256]
}

// ---------------------------------------------------------------------------
// k_fused: grid = 2*nbz + NHB.
//  [0,nbz)        : z  = fp16(h @ W_fc)     (v_dot2_f32_f16)
//  [nbz,2nbz)     : dz = fp16(feat @ W_dst) (v_dot2_f32_f16)
//  [2nbz,2nbz+NHB): bucket histogram of dst>>8 (LDS-aggregated, 196 counters)
// Thread tiling 4 nodes x 8 cols; LDS tiles PADDED (stride 33/17 uint2) so
// the wave's 4 broadcast groups hit 4 distinct banks (r20: stride-32 rows
// put all groups in bank 0 -> 1.26M conflicts).
// ---------------------------------------------------------------------------
__global__ __launch_bounds__(256) void k_fused(
        const float* __restrict__ h, const float* __restrict__ feat,
        const unsigned* __restrict__ Wfp, const unsigned* __restrict__ Wdp,
        unsigned short* __restrict__ z_h, unsigned short* __restrict__ dz_h,
        int N, int nbz,
        const int* __restrict__ dst, unsigned* __restrict__ bcounts, int E, int nbkt) {
    int t  = threadIdx.x;        // 0..255
    int b  = blockIdx.x;

    __shared__ uint2 sh[NB * HPAD];   // 16.5 KB (padded GEMM tiles); reused as hist

    if (b >= 2 * nbz) {
        // ---- bucket histogram partition ----
        unsigned* hist = (unsigned*)sh;
        int hb = b - 2 * nbz;
        hist[t] = 0;
        __syncthreads();
        for (int i = hb * 256 + t; i < E; i += NHB * 256)
            atomicAdd(&hist[dst[i] >> 8], 1u);
        __syncthreads();
        if (t < nbkt && hist[t]) atomicAdd(&bcounts[t], hist[t]);
        return;
    }

    int c  = t & 15;             // col chunks c and c+16 (cols 4c..4c+3, 4c+64..4c+67)
    int j0 = t >> 4;             // 0..15 -> nodes n0 + 4*j0 + jj (jj<4)
    bool do_z = (b < nbz);
    int n0 = (do_z ? b : b - nbz) * NB;

    float4 accA[4], accB[4];
#pragma unroll
    for (int jj = 0; jj < 4; ++jj) {
        accA[jj] = make_float4(0.f, 0.f, 0.f, 0.f);
        accB[jj] = make_float4(0.f, 0.f, 0.f, 0.f);
    }

    if (do_z) {
        // stage h tile fp16: [node][HPAD] uint2 (uint2 = 2 k-pairs = 4 k)
        for (int i = t; i < NB * 32; i += 256) {
            int row = i >> 5, col = i & 31;
            int n = min(n0 + row, N - 1);
            float4 v = ((const float4*)(h + (size_t)n * IN_DIM))[col];
            sh[row * HPAD + col] = make_uint2(f2h2(v.x, v.y), f2h2(v.z, v.w));
        }
        __syncthreads();

        const uint4* Wp4 = (const uint4*)Wfp;   // [k2][32] uint4
#pragma unroll 2
        for (int k4 = 0; k4 < 32; ++k4) {
            uint4 wA0 = Wp4[(size_t)(2 * k4) * 32 + c];
            uint4 wA1 = Wp4[(size_t)(2 * k4) * 32 + c + 16];
            uint4 wB0 = Wp4[(size_t)(2 * k4 + 1) * 32 + c];
            uint4 wB1 = Wp4[(size_t)(2 * k4 + 1) * 32 + c + 16];
#pragma unroll
            for (int jj = 0; jj < 4; ++jj) {
                uint2 q = sh[(j0 * 4 + jj) * HPAD + k4];
                accA[jj].x = dot2(q.y, wB0.x, dot2(q.x, wA0.x, accA[jj].x));
                accA[jj].y = dot2(q.y, wB0.y, dot2(q.x, wA0.y, accA[jj].y));
                accA[jj].z = dot2(q.y, wB0.z, dot2(q.x, wA0.z, accA[jj].z));
                accA[jj].w = dot2(q.y, wB0.w, dot2(q.x, wA0.w, accA[jj].w));
                accB[jj].x = dot2(q.y, wB1.x, dot2(q.x, wA1.x, accB[jj].x));
                accB[jj].y = dot2(q.y, wB1.y, dot2(q.x, wA1.y, accB[jj].y));
                accB[jj].z = dot2(q.y, wB1.z, dot2(q.x, wA1.z, accB[jj].z));
                accB[jj].w = dot2(q.y, wB1.w, dot2(q.x, wA1.w, accB[jj].w));
            }
        }
#pragma unroll
        for (int jj = 0; jj < 4; ++jj) {
            int n = n0 + j0 * 4 + jj;
            if (n < N) {
                uint2* zr = (uint2*)(z_h + (size_t)n * OUT_DIM);
                zr[c]      = make_uint2(f2h2(accA[jj].x, accA[jj].y),
                                        f2h2(accA[jj].z, accA[jj].w));
                zr[c + 16] = make_uint2(f2h2(accB[jj].x, accB[jj].y),
                                        f2h2(accB[jj].z, accB[jj].w));
            }
        }
    } else {
        // stage feat tile fp16: [node][FPAD] uint2
        for (int i = t; i < NB * 16; i += 256) {
            int row = i >> 4, col = i & 15;
            int n = min(n0 + row, N - 1);
            float4 v = ((const float4*)(feat + (size_t)n * FEAT_DIM))[col];
            sh[row * FPAD + col] = make_uint2(f2h2(v.x, v.y), f2h2(v.z, v.w));
        }
        __syncthreads();

        const uint4* Wd4 = (const uint4*)Wdp;   // [k2][32] uint4
#pragma unroll 2
        for (int k4 = 0; k4 < 16; ++k4) {
            uint4 wA0 = Wd4[(size_t)(2 * k4) * 32 + c];
            uint4 wA1 = Wd4[(size_t)(2 * k4) * 32 + c + 16];
            uint4 wB0 = Wd4[(size_t)(2 * k4 + 1) * 32 + c];
            uint4 wB1 = Wd4[(size_t)(2 * k4 + 1) * 32 + c + 16];
#pragma unroll
            for (int jj = 0; jj < 4; ++jj) {
                uint2 q = sh[(j0 * 4 + jj) * FPAD + k4];
                accA[jj].x = dot2(q.y, wB0.x, dot2(q.x, wA0.x, accA[jj].x));
                accA[jj].y = dot2(q.y, wB0.y, dot2(q.x, wA0.y, accA[jj].y));
                accA[jj].z = dot2(q.y, wB0.z, dot2(q.x, wA0.z, accA[jj].z));
                accA[jj].w = dot2(q.y, wB0.w, dot2(q.x, wA0.w, accA[jj].w));
                accB[jj].x = dot2(q.y, wB1.x, dot2(q.x, wA1.x, accB[jj].x));
                accB[jj].y = dot2(q.y, wB1.y, dot2(q.x, wA1.y, accB[jj].y));
                accB[jj].z = dot2(q.y, wB1.z, dot2(q.x, wA1.z, accB[jj].z));
                accB[jj].w = dot2(q.y, wB1.w, dot2(q.x, wA1.w, accB[jj].w));
            }
        }
#pragma unroll
        for (int jj = 0; jj < 4; ++jj) {
            int n = n0 + j0 * 4 + jj;
            if (n < N) {
                uint2* dr = (uint2*)(dz_h + (size_t)n * OUT_DIM);
                dr[c]      = make_uint2(f2h2(accA[jj].x, accA[jj].y),
                                        f2h2(accA[jj].z, accA[jj].w));
                dr[c + 16] = make_uint2(f2h2(accB[jj].x, accB[jj].y),
                                        f2h2(accB[jj].z, accB[jj].w));
            }
        }
    }
}

// ---------------------------------------------------------------------------
// k_bin: bin edges by bucket (dst>>8).  Each block computes the 196-bucket
// exclusive scan locally from bcounts, reserves space via breserve, writes
// payload = src | local_dst<<24 grouped (line-filling).
// ---------------------------------------------------------------------------
__global__ __launch_bounds__(256) void k_bin(
        const int* __restrict__ dst, const int* __restrict__ src,
        const unsigned* __restrict__ bcounts, unsigned* __restrict__ breserve,
        unsigned* __restrict__ binned, int E, int nbkt) {
    __shared__ unsigned bst[256];     // exclusive bucket starts
    __shared__ unsigned hist[256];
    __shared__ unsigned base[256];
    __shared__ unsigned cur[256];
    int t = threadIdx.x;

    unsigned v = (t < nbkt) ? bcounts[t] : 0u;
    bst[t] = v;
    __syncthreads();
    for (int off = 1; off < 256; off <<= 1) {
        unsigned u = (t >= off) ? bst[t - off] : 0u;
        __syncthreads();
        bst[t] += u;
        __syncthreads();
    }
    unsigned excl = bst[t] - v;
    __syncthreads();
    bst[t] = excl;
    hist[t] = 0;
    cur[t]  = 0;
    __syncthreads();

    int per = (E + gridDim.x - 1) / gridDim.x;
    int lo = blockIdx.x * per;
    int hi = min(E, lo + per);

    for (int i = lo + t; i < hi; i += 256)
        atomicAdd(&hist[dst[i] >> 8], 1u);
    __syncthreads();
    if (t < nbkt && hist[t]) base[t] = bst[t] + atomicAdd(&breserve[t], hist[t]);
    __syncthreads();
    for (int i = lo + t; i < hi; i += 256) {
        int d = dst[i];
        int bk = d >> 8;
        unsigned slot = base[bk] + atomicAdd(&cur[bk], 1u);
        binned[slot] = (unsigned)src[i] | ((unsigned)(d & 255) << 24);
    }
}

// ---------------------------------------------------------------------------
// k_sortx: block b owns bucket b.  Local scan of bcounts -> bucket window;
// stage bucket edges in LDS, per-dst LDS histogram + scan -> offsets + csr.
// ---------------------------------------------------------------------------
__global__ __launch_bounds__(256) void k_sortx(
        const unsigned* __restrict__ binned, const unsigned* __restrict__ bcounts,
        unsigned* __restrict__ offsets, unsigned* __restrict__ csr,
        int N, int E, int nbkt) {
    __shared__ unsigned ebuf[EBUF];     // 24 KB
    __shared__ unsigned bst[256];
    __shared__ unsigned lhist[256];
    __shared__ unsigned loffx[256];     // exclusive per-dst offsets
    __shared__ unsigned lcur[256];
    int b = blockIdx.x, t = threadIdx.x;

    unsigned v = (t < nbkt) ? bcounts[t] : 0u;
    bst[t] = v;
    __syncthreads();
    for (int off = 1; off < 256; off <<= 1) {
        unsigned u = (t >= off) ? bst[t - off] : 0u;
        __syncthreads();
        bst[t] += u;
        __syncthreads();
    }
    unsigned excl = bst[t] - v;
    __syncthreads();
    bst[t] = excl;
    lhist[t] = 0;
    lcur[t]  = 0;
    __syncthreads();

    unsigned lo = bst[b];
    int cnt = (int)((b < nbkt) ? bcounts[b] : 0u);
    int d0 = b << 8;
    int nd = min(N - d0, 256);
    bool fits = (cnt <= EBUF);

    if (fits) {
        for (int i = t; i < cnt; i += 256) {
            unsigned e = binned[lo + i];
            ebuf[i] = e;
            atomicAdd(&lhist[e >> 24], 1u);
        }
    } else {
        for (int i = t; i < cnt; i += 256)
            atomicAdd(&lhist[binned[lo + i] >> 24], 1u);
    }
    __syncthreads();

    unsigned lv = lhist[t];
    loffx[t] = lv;
    __syncthreads();
    for (int off = 1; off < 256; off <<= 1) {
        unsigned u = (t >= off) ? loffx[t - off] : 0u;
        __syncthreads();
        loffx[t] += u;
        __syncthreads();
    }
    unsigned lexcl = loffx[t] - lv;
    __syncthreads();
    loffx[t] = lexcl;
    __syncthreads();

    if (t < nd) offsets[d0 + t] = lo + lexcl;
    if (b == nbkt - 1 && t == 0) offsets[N] = (unsigned)E;

    if (fits) {
        for (int i = t; i < cnt; i += 256) {
            unsigned e = ebuf[i];
            int ld = (int)(e >> 24);
            unsigned pos = loffx[ld] + atomicAdd(&lcur[ld], 1u);
            csr[lo + pos] = e & 0xFFFFFFu;
        }
    } else {
        for (int i = t; i < cnt; i += 256) {
            unsigned e = binned[lo + i];
            int ld = (int)(e >> 24);
            unsigned pos = loffx[ld] + atomicAdd(&lcur[ld], 1u);
            csr[lo + pos] = e & 0xFFFFFFu;
        }
    }
}

// ---------------------------------------------------------------------------
// Fused attention + aggregation. One 64-lane wave per node (4 nodes/block).
// 16 lanes per edge; z AND dz rows in FP16 (256 B/row, one uint4/lane).
// ---------------------------------------------------------------------------
__global__ __launch_bounds__(256) void k_node(
        const unsigned short* __restrict__ z_h, const unsigned short* __restrict__ dz_h,
        const unsigned* __restrict__ offsets, const unsigned* __restrict__ csr,
        float* __restrict__ out, int N) {
    int lane = threadIdx.x & 63;
    int wv   = threadIdx.x >> 6;          // 0..3
    int g    = lane >> 4;                 // edge slot 0..3
    int l16  = lane & 15;                 // row chunk: dims [8*l16, 8*l16+8)
    int n = blockIdx.x * 4 + wv;
    if (n >= N) return;

    unsigned start = offsets[n];
    int deg = (int)(offsets[n + 1] - start);
    float4* orow = (float4*)(out + (size_t)n * OUT_DIM);
    if (deg == 0) {
        if (g == 0) {
            orow[2 * l16]     = make_float4(0.f, 0.f, 0.f, 0.f);
            orow[2 * l16 + 1] = make_float4(0.f, 0.f, 0.f, 0.f);
        }
        return;
    }

    uint4 dq = ((const uint4*)(dz_h + (size_t)n * OUT_DIM))[l16];  // 8 fp16 dims

    float a[8];
#pragma unroll
    for (int k = 0; k < 8; ++k) a[k] = 0.f;
    float denom = 0.f;

    for (int i = 0; i < deg; i += 8) {
        int eA = i + g;
        int eB = i + 4 + g;
        bool vA = eA < deg;
        bool vB = eB < deg;
        int sA = vA ? (int)csr[start + eA] : 0;
        int sB = vB ? (int)csr[start + eB] : 0;
        uint4 qA = ((const uint4*)(z_h + (size_t)sA * OUT_DIM))[l16];
        uint4 qB = ((const uint4*)(z_h + (size_t)sB * OUT_DIM))[l16];

        float pA = dot2(qA.w, dq.w, dot2(qA.z, dq.z, dot2(qA.y, dq.y, dot2(qA.x, dq.x, 0.f))));
        float pB = dot2(qB.w, dq.w, dot2(qB.z, dq.z, dot2(qB.y, dq.y, dot2(qB.x, dq.x, 0.f))));
#pragma unroll
        for (int off = 1; off <= 8; off <<= 1) {   // reduce within 16-lane group
            pA += __shfl_xor(pA, off);
            pB += __shfl_xor(pB, off);
        }
        float wA = vA ? __expf(pA) : 0.f;
        float wB = vB ? __expf(pB) : 0.f;
        denom += wA + wB;

        float2 zA01 = h2f2(qA.x), zA23 = h2f2(qA.y), zA45 = h2f2(qA.z), zA67 = h2f2(qA.w);
        float2 zB01 = h2f2(qB.x), zB23 = h2f2(qB.y), zB45 = h2f2(qB.z), zB67 = h2f2(qB.w);
        a[0] += wA * zA01.x + wB * zB01.x;  a[1] += wA * zA01.y + wB * zB01.y;
        a[2] += wA * zA23.x + wB * zB23.x;  a[3] += wA * zA23.y + wB * zB23.y;
        a[4] += wA * zA45.x + wB * zB45.x;  a[5] += wA * zA45.y + wB * zB45.y;
        a[6] += wA * zA67.x + wB * zB67.x;  a[7] += wA * zA67.y + wB * zB67.y;
    }

    // fold the 4 edge-groups together (lanes l, l^16, l^32, l^48)
#pragma unroll
    for (int off = 16; off <= 32; off <<= 1) {
#pragma unroll
        for (int k = 0; k < 8; ++k) a[k] += __shfl_xor(a[k], off);
        denom += __shfl_xor(denom, off);
    }

    if (g == 0) {
        float inv = 1.f / denom;
        orow[2 * l16]     = make_float4(a[0] * inv, a[1] * inv, a[2] * inv, a[3] * inv);
        orow[2 * l16 + 1] = make_float4(a[4] * inv, a[5] * inv, a[6] * inv, a[7] * inv);
    }
}

// ---------------------------------------------------------------------------
extern "C" void kernel_launch(void* const* d_in, const int* in_sizes, int n_in,
                              void* d_out, int out_size, void* d_ws, size_t ws_size,
                              hipStream_t stream) {
    const float* h    = (const float*)d_in[0];
    const float* feat = (const float*)d_in[1];
    const float* Wfc  = (const float*)d_in[2];
    const float* Wdst = (const float*)d_in[3];
    const int*   src  = (const int*)d_in[4];
    const int*   dst  = (const int*)d_in[5];
    float*       out  = (float*)d_out;

    int N = in_sizes[0] / IN_DIM;
    int E = in_sizes[4];

    char* ws = (char*)d_ws;
    unsigned short* z_h  = (unsigned short*)ws; ws += (size_t)N * OUT_DIM * sizeof(unsigned short);
    unsigned short* dz_h = (unsigned short*)ws; ws += (size_t)N * OUT_DIM * sizeof(unsigned short);
    unsigned* Wfp      = (unsigned*)ws; ws += (size_t)8192 * sizeof(unsigned);
    unsigned* Wdp      = (unsigned*)ws; ws += (size_t)4096 * sizeof(unsigned);
    unsigned* binned   = (unsigned*)ws; ws += (size_t)E * sizeof(unsigned);
    unsigned* bcounts  = (unsigned*)ws; ws += (size_t)256 * sizeof(unsigned);
    unsigned* breserve = (unsigned*)ws; ws += (size_t)256 * sizeof(unsigned);
    unsigned* offsets  = (unsigned*)ws; ws += (size_t)(N + 1) * sizeof(unsigned);
    unsigned* csr      = (unsigned*)ws;

    int nbz  = (N + NB - 1) / NB;        // 782
    int nbkt = (N + 255) / 256;          // 196 buckets

    k_wt    <<<48, 256, 0, stream>>>(Wfc, Wdst, Wfp, Wdp, bcounts);  // bcounts+breserve adjacent
    k_fused <<<2 * nbz + NHB, 256, 0, stream>>>(h, feat, Wfp, Wdp, z_h, dz_h,
                                                N, nbz, dst, bcounts, E, nbkt);
    k_bin   <<<512, 256, 0, stream>>>(dst, src, bcounts, breserve, binned, E, nbkt);
    k_sortx <<<nbkt, 256, 0, stream>>>(binned, bcounts, offsets, csr, N, E, nbkt);
    k_node  <<<(N + 3) / 4, 256, 0, stream>>>(z_h, dz_h, offsets, csr, out, N);
}